// Round 2
// baseline (1031.091 us; speedup 1.0000x reference)
//
#include <hip/hip_runtime.h>
#include <hip/hip_cooperative_groups.h>

namespace cg = cooperative_groups;

using ull = unsigned long long;

// ---------------- problem constants ----------------
constexpr int NB  = 32;
constexpr int HW0 = 320 * 320;
constexpr int HW1 = 160 * 160;
constexpr int N0  = NB * HW0;            // 3,276,800
constexpr int N1  = NB * HW1;            // 819,200
constexpr int HW0_4 = HW0 / 4;
constexpr int HW1_4 = HW1 / 4;
constexpr int BLK = 256;

// score blocks: 2 uint4-packs (8 px) per thread -> 512 packs per block
constexpr int SB0 = N0 / 4 / 512;        // 1600
constexpr int SB1 = N1 / 4 / 512;        // 400
constexpr int SBT = SB0 + SB1;           // 2000
// bbox blocks: 5 float4 per stream per thread, fully unrolled
constexpr int BBLK0 = 2560, BBLK1 = 640; // 3,276,800/(2560*256)=5 ; 819,200/(640*256)=5
constexpr int P1_GRID = SBT + BBLK0 + BBLK1;   // 5200
// refine: 4 uint4-packs (16 px) per thread
constexpr int RB0 = 800, RB1 = 200, GRID_R = RB0 + RB1;
constexpr int RT0 = RB0 * BLK;           // 204,800 (uint4 stride)
constexpr int RT1 = RB1 * BLK;           // 51,200

constexpr float CE_SCALE = 16384.0f;
constexpr ull MASK40 = (1ull << 40) - 1;
constexpr int REP1 = 32, REP2 = 8;

// ---------------- workspace layout (bytes) ----------------
constexpr size_t CTRL_OFF = 0;                                   // BranchCtrl[2]
constexpr size_t ACC_OFF  = 256;                                 // Acc[2] (within zeroed page)
constexpr size_t H1_OFF  = 4096;                                 // u32 [2][1024][REP1] (bin-major)
constexpr size_t H2_OFF  = H1_OFF + (size_t)2 * 1024 * REP1 * 4; // u32 [2][2048][REP2]
constexpr size_t H3_OFF  = H2_OFF + (size_t)2 * 2048 * REP2 * 4; // u64 [2][1024][REP2]
constexpr size_t FIN_OFF = H3_OFF + (size_t)2 * 1024 * REP2 * 8; // [2][REP2][2] u64 cnt, double ce
constexpr size_t ZERO_END = FIN_OFF + 2 * REP2 * 16;             // 528,640
constexpr int    ZERO_V4  = (int)(ZERO_END / 16);                // 33,040 uint4s
constexpr size_t PN_OFF  = ZERO_END;                             // u32[SBT]
constexpr size_t CEP_OFF = PN_OFF + SBT * 4;                     // double2[SBT] (ce0, ce1nn)
constexpr size_t DM_OFF  = CEP_OFF + (size_t)SBT * 16;           // double2[3200] (d2, ms)
// compact reduction outputs (written-before-read each launch; no zeroing needed)
constexpr size_t CN1_OFF = DM_OFF + (size_t)3200 * 16;           // u32[2][1024]
constexpr size_t CN2_OFF = CN1_OFF + (size_t)2 * 1024 * 4;       // u32[2][2048]
constexpr size_t CEV_OFF = CN2_OFF + (size_t)2 * 2048 * 4;       // u64[2][1024]
constexpr size_t PB_OFF  = ((CEV_OFF + (size_t)2 * 1024 * 8 + 255) / 256) * 256;
constexpr size_t WS_NEED = PB_OFF + (size_t)(N0 + N1) * 4;       // ~17.05 MB

struct BranchCtrl {
    unsigned pos_num, neg_num, sel1, sel2, target, done, pad0, pad1;
    double ce0, ce1nn, loss_score, loss_bbox;
};
struct Acc { ull pn; double ce0, ce1, d2, ms; };

__device__ inline BranchCtrl* ctrl_of(void* ws, int br) { return (BranchCtrl*)((char*)ws + CTRL_OFF) + br; }
__device__ inline Acc*      acc_of(void* ws)       { return (Acc*)((char*)ws + ACC_OFF); }
__device__ inline unsigned* h1_of(void* ws, int br) { return (unsigned*)((char*)ws + H1_OFF) + (size_t)br * 1024 * REP1; }
__device__ inline unsigned* h2_of(void* ws, int br) { return (unsigned*)((char*)ws + H2_OFF) + (size_t)br * 2048 * REP2; }
__device__ inline ull*      h3_of(void* ws, int br) { return (ull*)((char*)ws + H3_OFF) + (size_t)br * 1024 * REP2; }
__device__ inline ull*      fin_of(void* ws, int br) { return (ull*)((char*)ws + FIN_OFF) + (size_t)br * REP2 * 2; }
__device__ inline unsigned* pn_part(void* ws)  { return (unsigned*)((char*)ws + PN_OFF); }
__device__ inline double2*  cep_part(void* ws) { return (double2*)((char*)ws + CEP_OFF); }
__device__ inline double2*  dm_part(void* ws)  { return (double2*)((char*)ws + DM_OFF); }
__device__ inline unsigned* cnt1_of(void* ws)  { return (unsigned*)((char*)ws + CN1_OFF); }
__device__ inline unsigned* cnt2_of(void* ws)  { return (unsigned*)((char*)ws + CN2_OFF); }
__device__ inline ull*      cev_of(void* ws)   { return (ull*)((char*)ws + CEV_OFF); }
__device__ inline unsigned* pb_of(void* ws, int br) { return (unsigned*)((char*)ws + PB_OFF) + (br ? (size_t)N0 : 0); }

// ---------------- reduce helpers ----------------
__device__ __forceinline__ unsigned wred_u(unsigned v) {
#pragma unroll
    for (int o = 32; o > 0; o >>= 1) v += __shfl_down(v, o, 64);
    return v;
}
__device__ __forceinline__ ull wred_q(ull v) {
#pragma unroll
    for (int o = 32; o > 0; o >>= 1) v += __shfl_down(v, o, 64);
    return v;
}
__device__ __forceinline__ double wred_d(double v) {
#pragma unroll
    for (int o = 32; o > 0; o >>= 1) v += __shfl_down(v, o, 64);
    return v;
}

// ---------------- kernels ----------------
__global__ __launch_bounds__(256) void zero_ws_k(uint4* p, int n) {
    int i = blockIdx.x * BLK + threadIdx.x;
    if (i < n) p[i] = make_uint4(0, 0, 0, 0);
}

// ---- pass1 (unchanged from 325 us baseline) ----
template <int BR, bool STORED>
__device__ void score_body(const float4* __restrict__ score, const float4* __restrict__ glabel,
                           void* ws, int blk, int gblk, unsigned* h)
{
    constexpr int HW4 = BR ? HW1_4 : HW0_4;
    const int t = threadIdx.x;
    const int base = blk * 512 + t;

    float4 s0[2], s1[2], g0[2], g1[2];
    int idx[2] = { base, base + 256 };
#pragma unroll
    for (int u = 0; u < 2; u++) {
        int b = idx[u] / HW4, r = idx[u] - b * HW4;
        const float4* sp = score  + (size_t)(b * 2) * HW4 + r;
        const float4* gp = glabel + (size_t)(b * 6) * HW4 + r;
        s0[u] = sp[0]; s1[u] = sp[HW4];
        g0[u] = gp[0]; g1[u] = gp[HW4];
    }

    unsigned posc = 0, negc = 0;
    float ce0 = 0.0f, ce1 = 0.0f;
#pragma unroll
    for (int u = 0; u < 2; u++) {
        uint4 pk;
        unsigned bins[4];
#pragma unroll
        for (int j = 0; j < 4; j++) {
            float a = (&s0[u].x)[j], cc = (&s1[u].x)[j];
            float m = fmaxf(a, cc);
            float e0 = __expf(a - m), e1 = __expf(cc - m);
            float inv = 1.0f / (e0 + e1);
            float p0 = e0 * inv, p1 = e1 * inv;
            float l0 = (&g0[u].x)[j], l1 = (&g1[u].x)[j];
            bool pos = l0 > 0.5f, neg = l1 > 0.5f;
            posc += pos ? 1u : 0u;
            negc += neg ? 1u : 0u;
            if (pos)  ce0 += -l0 * __logf(p0);
            if (!neg) ce1 += -l1 * __logf(p1);
            unsigned pb = __float_as_uint(p1);
            (&pk.x)[j] = pb | (neg ? 0x80000000u : 0u);
            bins[j] = (neg ? 0u : 512u) + (pb >> 21);
        }
        if (STORED) ((uint4*)pb_of(ws, BR))[idx[u]] = pk;
#pragma unroll
        for (int j = 0; j < 4; j++) {
            unsigned bj = bins[j];
            if (bj != 0xFFFFFFFFu) {
                unsigned cnt = 1;
#pragma unroll
                for (int k = j + 1; k < 4; k++)
                    if (bins[k] == bj) { cnt++; bins[k] = 0xFFFFFFFFu; }
                atomicAdd(&h[bj], cnt);
            }
        }
    }

    unsigned pn = posc | (negc << 16);
    pn = wred_u(pn);
    double C0 = wred_d((double)ce0);
    double C1 = wred_d((double)ce1);
    __shared__ unsigned spn[4];
    __shared__ double sc0[4], sc1[4];
    int w = t >> 6, lane = t & 63;
    if (lane == 0) { spn[w] = pn; sc0[w] = C0; sc1[w] = C1; }
    __syncthreads();   // also orders LDS hist atomics before flush
    if (t == 0) {
        pn_part(ws)[gblk] = spn[0] + spn[1] + spn[2] + spn[3];
        cep_part(ws)[gblk] = make_double2(sc0[0] + sc0[1] + sc0[2] + sc0[3],
                                          sc1[0] + sc1[1] + sc1[2] + sc1[3]);
    }
    const int rep = gblk & (REP1 - 1);
    unsigned* H = h1_of(ws, BR);
    for (int i = t; i < 1024; i += BLK) {
        unsigned v = h[i];
        if (v) atomicAdd(&H[(size_t)i * REP1 + rep], v);
    }
}

template <int BR>
__device__ void bbox_body(const float4* __restrict__ bbox, const float4* __restrict__ gmask,
                          const float4* __restrict__ glabel, void* ws, int blk, int gblk)
{
    constexpr int HW4 = BR ? HW1_4 : HW0_4;
    constexpr int NT  = (BR ? BBLK1 : BBLK0) * BLK;
    const int t = threadIdx.x;
    const int i0 = blk * BLK + t;
    float d2 = 0.0f, ms = 0.0f;
#pragma unroll
    for (int k = 0; k < 5; k++) {
        int i = i0 + k * NT;
        int b = i / (4 * HW4);
        int off = i + (2 * b + 2) * HW4;
        float4 pb4 = bbox[i];
        float4 gm  = gmask[off];
        float4 gl  = glabel[off];
#pragma unroll
        for (int j = 0; j < 4; j++) {
            float m = (&gm.x)[j];
            float d = ((&pb4.x)[j] - (&gl.x)[j]) * m;
            d2 += d * d;
            ms += m;
        }
    }
    double D = wred_d((double)d2);
    double M = wred_d((double)ms);
    __shared__ double sdd[4], sdm[4];
    int w = t >> 6, lane = t & 63;
    if (lane == 0) { sdd[w] = D; sdm[w] = M; }
    __syncthreads();
    if (t == 0)
        dm_part(ws)[gblk] = make_double2(sdd[0] + sdd[1] + sdd[2] + sdd[3],
                                         sdm[0] + sdm[1] + sdm[2] + sdm[3]);
}

template <bool STORED>
__global__ __launch_bounds__(256, 4) void pass1(
    const float4* __restrict__ sc0, const float4* __restrict__ bb0,
    const float4* __restrict__ mk0, const float4* __restrict__ lb0,
    const float4* __restrict__ sc1, const float4* __restrict__ bb1,
    const float4* __restrict__ mk1, const float4* __restrict__ lb1,
    void* ws)
{
    __shared__ unsigned h[1024];
    const int bid = blockIdx.x;
    if (bid < SBT) {
        for (int i = threadIdx.x; i < 1024; i += BLK) h[i] = 0;
        __syncthreads();
        if (bid < SB0) score_body<0, STORED>(sc0, lb0, ws, bid, bid, h);
        else           score_body<1, STORED>(sc1, lb1, ws, bid - SB0, bid, h);
    } else if (bid < SBT + BBLK0) {
        bbox_body<0>(bb0, mk0, lb0, ws, bid - SBT, bid - SBT);
    } else {
        bbox_body<1>(bb1, mk1, lb1, ws, bid - SBT - BBLK0, bid - SBT);
    }
}

// ---- refine2 body: count hist of mid-bits within sel1 bin (unchanged) ----
template <int BR, bool STORED>
__device__ void refine2_body(const float4* __restrict__ score, const float4* __restrict__ glabel,
                             void* ws, int blk, unsigned* h)
{
    BranchCtrl* c = ctrl_of(ws, BR);
    const unsigned haspos = (c->pos_num > 0) ? 1u : 0u;
    const unsigned sel1 = c->sel1;
    constexpr int T = BR ? RT1 : RT0;
    constexpr int HW4 = BR ? HW1_4 : HW0_4;
    const int base = blk * BLK + (int)threadIdx.x;

    unsigned pk[16];
    if (STORED) {
        const uint4* pb4 = (const uint4*)pb_of(ws, BR);
#pragma unroll
        for (int i = 0; i < 4; i++) {
            uint4 q = pb4[base + i * T];
            pk[i*4+0]=q.x; pk[i*4+1]=q.y; pk[i*4+2]=q.z; pk[i*4+3]=q.w;
        }
    } else {
#pragma unroll
        for (int i = 0; i < 4; i++) {
            int id = base + i * T;
            int b = id / HW4, r = id - b * HW4;
            float4 s0 = score[(size_t)(b*2)*HW4 + r];
            float4 s1 = score[(size_t)(b*2+1)*HW4 + r];
            float4 g1 = glabel[(size_t)(b*6+1)*HW4 + r];
#pragma unroll
            for (int j = 0; j < 4; j++) {
                float a=(&s0.x)[j], cc=(&s1.x)[j];
                float m=fmaxf(a,cc);
                float e0=__expf(a-m), e1=__expf(cc-m);
                float p1=e1/(e0+e1);
                pk[i*4+j] = __float_as_uint(p1) | (((&g1.x)[j] > 0.5f) ? 0x80000000u : 0u);
            }
        }
    }
    unsigned z = 0;
#pragma unroll
    for (int i = 0; i < 4; i++) {
        unsigned bins[4];
#pragma unroll
        for (int j = 0; j < 4; j++) {
            unsigned raw = pk[i*4+j], pbv = raw & 0x7FFFFFFFu;
            unsigned npb = haspos ? ((raw >> 31) ? pbv : 0u) : pbv;
            bool m = (npb >> 21) == sel1;
            if (m && npb == 0) { z++; bins[j] = 0xFFFFFFFFu; }
            else bins[j] = m ? ((npb >> 10) & 0x7FFu) : 0xFFFFFFFFu;
        }
#pragma unroll
        for (int j = 0; j < 4; j++) {
            unsigned bj = bins[j];
            if (bj != 0xFFFFFFFFu) {
                unsigned cnt = 1;
#pragma unroll
                for (int k = j + 1; k < 4; k++)
                    if (bins[k] == bj) { cnt++; bins[k] = 0xFFFFFFFFu; }
                atomicAdd(&h[bj], cnt);
            }
        }
    }
    if (z) atomicAdd(&h[0], z);
}

// ---- refine3 body: low-bits hist (cnt+cefx) within sel1:sel2, plus strictly-below gather (unchanged) ----
template <int BR, bool STORED>
__device__ void refine3_body(const float4* __restrict__ score, const float4* __restrict__ glabel,
                             void* ws, int blk, int gblk, ull* h)
{
    BranchCtrl* c = ctrl_of(ws, BR);
    const unsigned haspos = (c->pos_num > 0) ? 1u : 0u;
    const unsigned sel1 = c->sel1, sel2 = c->sel2;
    const unsigned sel12 = (sel1 << 11) | sel2;
    constexpr int T = BR ? RT1 : RT0;
    constexpr int HW4 = BR ? HW1_4 : HW0_4;
    constexpr int HW  = BR ? HW1 : HW0;
    const int base = blk * BLK + (int)threadIdx.x;
    const float* glab_s = (const float*)glabel;

    unsigned pk[16];
    float g1v[16];
    if (STORED) {
        const uint4* pb4 = (const uint4*)pb_of(ws, BR);
#pragma unroll
        for (int i = 0; i < 4; i++) {
            uint4 q = pb4[base + i * T];
            pk[i*4+0]=q.x; pk[i*4+1]=q.y; pk[i*4+2]=q.z; pk[i*4+3]=q.w;
        }
    } else {
#pragma unroll
        for (int i = 0; i < 4; i++) {
            int id = base + i * T;
            int b = id / HW4, r = id - b * HW4;
            float4 s0 = score[(size_t)(b*2)*HW4 + r];
            float4 s1 = score[(size_t)(b*2+1)*HW4 + r];
            float4 g1 = glabel[(size_t)(b*6+1)*HW4 + r];
#pragma unroll
            for (int j = 0; j < 4; j++) {
                float a=(&s0.x)[j], cc=(&s1.x)[j];
                float m=fmaxf(a,cc);
                float e0=__expf(a-m), e1=__expf(cc-m);
                float p1=e1/(e0+e1);
                pk[i*4+j] = __float_as_uint(p1) | (((&g1.x)[j] > 0.5f) ? 0x80000000u : 0u);
                g1v[i*4+j] = (&g1.x)[j];
            }
        }
    }

    ull cnt_lt = 0;
    double ce_lt = 0.0;
    ull zpack = 0;
#pragma unroll
    for (int i = 0; i < 4; i++) {
#pragma unroll
        for (int j = 0; j < 4; j++) {
            unsigned raw = pk[i*4+j], pbv = raw & 0x7FFFFFFFu;
            unsigned npb = haspos ? ((raw >> 31) ? pbv : 0u) : pbv;
            bool iszero = (npb == 0);
            if (iszero && sel12 != 0) continue;  // accounted via base in scan3
            unsigned b1 = npb >> 21, b2 = (npb >> 10) & 0x7FFu;
            bool lt = (b1 < sel1) || (b1 == sel1 && b2 < sel2);
            bool eq = ((npb >> 10) == sel12);
            if (lt || eq) {
                float g1s;
                if (STORED) {
                    int px = (base + i * T) * 4 + j;
                    int bb = px / HW, rr = px - bb * HW;
                    g1s = glab_s[(size_t)(bb * 6 + 1) * HW + rr];
                } else {
                    g1s = g1v[i*4+j];
                }
                float ce = -g1s * __logf(__uint_as_float(pbv));
                if (lt) { cnt_lt++; ce_lt += (double)ce; }
                else {
                    ull v = (1ull << 40) | (ull)__float2uint_rn(ce * CE_SCALE);
                    if (iszero) zpack += v;
                    else atomicAdd(&h[npb & 0x3FFu], v);
                }
            }
        }
    }
    if (zpack) atomicAdd(&h[0], zpack);

    ull CL = wred_q(cnt_lt);
    double CE = wred_d(ce_lt);
    __shared__ ull sq[4];
    __shared__ double sd[4];
    int t = threadIdx.x, w = t >> 6, lane = t & 63;
    if (lane == 0) { sq[w] = CL; sd[w] = CE; }
    __syncthreads();   // also orders LDS hist atomics before flush
    if (t == 0) {
        ull totc = sq[0] + sq[1] + sq[2] + sq[3];
        double totd = sd[0] + sd[1] + sd[2] + sd[3];
        ull* F = fin_of(ws, BR) + (size_t)(gblk & (REP2 - 1)) * 2;
        if (totc) atomicAdd(&F[0], totc);
        if (totd != 0.0) atomicAdd((double*)&F[1], totd);
    }
    const int rep = gblk & (REP2 - 1);
    ull* H = h3_of(ws, BR);
    for (int i = t; i < 1024; i += BLK) {
        ull v = h[i];
        if (v) atomicAdd(&H[(size_t)i * REP2 + rep], v);
    }
}

// ===================================================================
// FALLBACK PATH (baseline tail, known-good): refine2 / refine3 / scan_pass
// ===================================================================
template <bool STORED>
__global__ __launch_bounds__(256) void refine2_k(
    const float4* __restrict__ sc0, const float4* __restrict__ lb0,
    const float4* __restrict__ sc1, const float4* __restrict__ lb1, void* ws)
{
    int br, blk;
    if (blockIdx.x < RB0) { br = 0; blk = blockIdx.x; }
    else                  { br = 1; blk = blockIdx.x - RB0; }
    if (ctrl_of(ws, br)->done) return;

    __shared__ unsigned h[2048];
    for (int i = threadIdx.x; i < 2048; i += BLK) h[i] = 0;
    __syncthreads();
    if (br == 0) refine2_body<0, STORED>(sc0, lb0, ws, blk, h);
    else         refine2_body<1, STORED>(sc1, lb1, ws, blk, h);
    __syncthreads();
    const int rep = blockIdx.x & (REP2 - 1);
    unsigned* H = h2_of(ws, br);
    for (int i = threadIdx.x; i < 2048; i += BLK) {
        unsigned v = h[i];
        if (v) atomicAdd(&H[(size_t)i * REP2 + rep], v);
    }
}

template <bool STORED>
__global__ __launch_bounds__(256) void refine3_k(
    const float4* __restrict__ sc0, const float4* __restrict__ lb0,
    const float4* __restrict__ sc1, const float4* __restrict__ lb1, void* ws)
{
    int br, blk;
    if (blockIdx.x < RB0) { br = 0; blk = blockIdx.x; }
    else                  { br = 1; blk = blockIdx.x - RB0; }
    if (ctrl_of(ws, br)->done) return;

    __shared__ ull h[1024];
    for (int i = threadIdx.x; i < 1024; i += BLK) h[i] = 0;
    __syncthreads();
    if (br == 0) refine3_body<0, STORED>(sc0, lb0, ws, blk, blockIdx.x, h);
    else         refine3_body<1, STORED>(sc1, lb1, ws, blk, blockIdx.x, h);
}

__global__ __launch_bounds__(256) void scan_pass(void* ws, int level, float* out)
{
    const int t = threadIdx.x;
    __shared__ unsigned pref[256];
    __shared__ unsigned sh_sel, sh_tnext, sh_hA0;
    __shared__ unsigned shP[2], shN[2];
    __shared__ double shCE0[2], shCE1[2];
    __shared__ ull qscr[4];

    if (level == 1) {
        ull pn0 = 0, pn1 = 0;
        double a0=0, b0=0, a1=0, b1=0, d20=0, ms0=0, d21=0, ms1=0;
        const unsigned* PN = pn_part(ws);
        const double2* CP = cep_part(ws);
        for (int i = t; i < SBT; i += BLK) {
            unsigned v = PN[i];
            double2 ce = CP[i];
            ull pv = (ull)(v & 0xFFFFu) | ((ull)(v >> 16) << 32);
            if (i < SB0) { pn0 += pv; a0 += ce.x; b0 += ce.y; }
            else         { pn1 += pv; a1 += ce.x; b1 += ce.y; }
        }
        const double2* DM = dm_part(ws);
        for (int i = t; i < BBLK0 + BBLK1; i += BLK) {
            double2 d = DM[i];
            if (i < BBLK0) { d20 += d.x; ms0 += d.y; }
            else           { d21 += d.x; ms1 += d.y; }
        }
        pn0 = wred_q(pn0); pn1 = wred_q(pn1);
        a0 = wred_d(a0); b0 = wred_d(b0); a1 = wred_d(a1); b1 = wred_d(b1);
        d20 = wred_d(d20); ms0 = wred_d(ms0); d21 = wred_d(d21); ms1 = wred_d(ms1);
        __shared__ ull qs[2][4];
        __shared__ double ds[8][4];
        int w = t >> 6;
        if ((t & 63) == 0) {
            qs[0][w]=pn0; qs[1][w]=pn1;
            ds[0][w]=a0; ds[1][w]=b0; ds[2][w]=a1; ds[3][w]=b1;
            ds[4][w]=d20; ds[5][w]=ms0; ds[6][w]=d21; ds[7][w]=ms1;
        }
        __syncthreads();
        if (t == 0) {
            ull P0=qs[0][0]+qs[0][1]+qs[0][2]+qs[0][3];
            ull P1=qs[1][0]+qs[1][1]+qs[1][2]+qs[1][3];
            double A0=ds[0][0]+ds[0][1]+ds[0][2]+ds[0][3];
            double B0=ds[1][0]+ds[1][1]+ds[1][2]+ds[1][3];
            double A1=ds[2][0]+ds[2][1]+ds[2][2]+ds[2][3];
            double B1=ds[3][0]+ds[3][1]+ds[3][2]+ds[3][3];
            double D0=ds[4][0]+ds[4][1]+ds[4][2]+ds[4][3];
            double M0=ds[5][0]+ds[5][1]+ds[5][2]+ds[5][3];
            double D1=ds[6][0]+ds[6][1]+ds[6][2]+ds[6][3];
            double M1=ds[7][0]+ds[7][1]+ds[7][2]+ds[7][3];
            shP[0]=(unsigned)(P0 & 0xFFFFFFFFu); shN[0]=(unsigned)(P0 >> 32);
            shP[1]=(unsigned)(P1 & 0xFFFFFFFFu); shN[1]=(unsigned)(P1 >> 32);
            shCE0[0]=A0; shCE1[0]=B0; shCE0[1]=A1; shCE1[1]=B1;
            BranchCtrl* c0 = ctrl_of(ws, 0);
            BranchCtrl* c1 = ctrl_of(ws, 1);
            c0->pos_num=shP[0]; c0->neg_num=shN[0]; c0->ce0=A0; c0->ce1nn=B0;
            c1->pos_num=shP[1]; c1->neg_num=shN[1]; c1->ce0=A1; c1->ce1nn=B1;
            c0->loss_bbox = (M0 > 0.0) ? D0 / fmax(M0, 1e-8) : 0.0;
            c1->loss_bbox = (M1 > 0.0) ? D1 / fmax(M1, 1e-8) : 0.0;
        }
        __syncthreads();
    }

    for (int br = 0; br < 2; br++) {
        BranchCtrl* c = ctrl_of(ws, br);
        const unsigned N = br ? N1 : N0;
        unsigned target, haspos, negn, P;
        double CE0, CE1NN;
        if (level == 1) {
            P = shP[br]; negn = shN[br]; CE0 = shCE0[br]; CE1NN = shCE1[br];
            haspos = (P > 0) ? 1u : 0u;
            unsigned k = haspos ? ((5u * P < negn) ? 5u * P : negn) : (N / 10u);
            target = (k < 1u) ? 1u : k;
            if (target > N) target = N;
        } else {
            if (c->done) continue;
            P = c->pos_num; negn = c->neg_num; haspos = (P > 0) ? 1u : 0u;
            target = c->target; CE0 = c->ce0; CE1NN = c->ce1nn;
        }

        const int per = (level == 1) ? 2 : (level == 2) ? 8 : 4;
        unsigned cnt[8];
        ull cev[4];
        unsigned ssum = 0;
        if (level == 1) {
            const unsigned* H = h1_of(ws, br);
            for (int j = 0; j < 2; j++) {
                int i = t * 2 + j;
                const uint4* p = (const uint4*)(H + (size_t)i * REP1);
                unsigned s = 0;
#pragma unroll
                for (int r = 0; r < REP1 / 4; r++) { uint4 q = p[r]; s += q.x + q.y + q.z + q.w; }
                if (i == 0) sh_hA0 = s;
                if (!haspos) {
                    const uint4* p2 = (const uint4*)(H + (size_t)(512 + i) * REP1);
#pragma unroll
                    for (int r = 0; r < REP1 / 4; r++) { uint4 q = p2[r]; s += q.x + q.y + q.z + q.w; }
                }
                unsigned cv = s + ((haspos && i == 0) ? (N - negn) : 0u);
                cnt[j] = cv; ssum += cv;
            }
        } else if (level == 2) {
            const unsigned* H = h2_of(ws, br);
            for (int j = 0; j < 8; j++) {
                int i = t * 8 + j;
                const uint4* p = (const uint4*)(H + (size_t)i * REP2);
                uint4 q0 = p[0], q1 = p[1];
                cnt[j] = q0.x + q0.y + q0.z + q0.w + q1.x + q1.y + q1.z + q1.w;
                ssum += cnt[j];
            }
        } else {
            const ull* H = h3_of(ws, br);
            for (int j = 0; j < 4; j++) {
                int i = t * 4 + j;
                ull e = 0;
#pragma unroll
                for (int r = 0; r < REP2; r++) e += H[(size_t)i * REP2 + r];
                cev[j] = e;
                cnt[j] = (unsigned)(e >> 40);
                ssum += cnt[j];
            }
        }
        if (t == 0) { sh_sel = 0; sh_tnext = 1; }
        __syncthreads();
        pref[t] = ssum;
        __syncthreads();
        for (int off = 1; off < 256; off <<= 1) {
            unsigned x = (t >= off) ? pref[t - off] : 0u;
            __syncthreads();
            pref[t] += x;
            __syncthreads();
        }
        unsigned tot = pref[255];
        if (target > tot) target = tot;
        unsigned before = pref[t] - ssum;
        for (int j = 0; j < per; j++) {
            if (tot && before < target && before + cnt[j] >= target) {
                sh_sel = (unsigned)(t * per + j);
                sh_tnext = target - before;
            }
            before += cnt[j];
        }
        __syncthreads();
        unsigned sel = sh_sel;

        if (level == 3) {
            ull cei = 0;
            for (int j = 0; j < per; j++) {
                unsigned bin = (unsigned)(t * per + j);
                if (bin <= sel) cei += cev[j];
            }
            cei = wred_q(cei);
            int w = t >> 6;
            if ((t & 63) == 0) qscr[w] = cei;
            __syncthreads();
            if (t == 0) {
                ull CEI = qscr[0] + qscr[1] + qscr[2] + qscr[3];
                const ull* F = fin_of(ws, br);
                ull cl = 0; double cel = 0.0;
                for (int r = 0; r < REP2; r++) {
                    cl += F[r * 2];
                    cel += ((const double*)F)[r * 2 + 1];
                }
                unsigned sel12 = (c->sel1 << 11) | c->sel2;
                double basec = (haspos && sel12 != 0) ? (double)(N - negn) : 0.0;
                double basee = (haspos && sel12 != 0) ? CE1NN : 0.0;
                double cntd = (double)P + basec + (double)cl + (double)(CEI >> 40);
                if (cntd < 1.0) cntd = 1.0;
                double ce = CE0 + basee + cel + (double)(CEI & MASK40) / (double)CE_SCALE;
                c->loss_score = ce / cntd;
            }
            __syncthreads();
        } else if (t == 0) {
            if (level == 1) {
                if (haspos && sel == 0 && sh_hA0 == 0) {
                    double cntd = (double)P + (double)(N - negn);
                    if (cntd < 1.0) cntd = 1.0;
                    c->loss_score = (CE0 + CE1NN) / cntd;
                    c->done = 1;
                } else {
                    c->sel1 = sel; c->target = sh_tnext;
                }
            } else {
                c->sel2 = sel; c->target = sh_tnext;
            }
        }
        __syncthreads();
    }

    if (level == 3 && t == 0) {
        BranchCtrl* c0 = ctrl_of(ws, 0);
        BranchCtrl* c1 = ctrl_of(ws, 1);
        out[0] = (float)(c0->loss_score + c0->loss_bbox + c1->loss_score + c1->loss_bbox);
        out[1] = (float)c0->loss_score;
        out[2] = (float)c0->loss_bbox;
        out[3] = (float)c1->loss_score;
        out[4] = (float)c1->loss_bbox;
    }
}

// ===================================================================
// COOPERATIVE PATH: fused tail. __launch_bounds__(256,2) -> VGPR cap 256,
// LDS 9.3 KB -> 2 blocks/CU structurally guaranteed; grid sized from the
// runtime occupancy query; refine phases are grid-stride over GRID_R tiles.
// ===================================================================
template <bool STORED>
__global__ __launch_bounds__(256, 2) void tail_k(
    const float4* __restrict__ sc0, const float4* __restrict__ lb0,
    const float4* __restrict__ sc1, const float4* __restrict__ lb1,
    void* ws, float* out)
{
    cg::grid_group grid = cg::this_grid();
    const int t = threadIdx.x;
    const int bid = blockIdx.x;
    const int nbl = gridDim.x;

    __shared__ ull SMEM[1024];          // hist union: u32[2048] (refine2) / ull[1024] (refine3)
    __shared__ unsigned pref[256];
    __shared__ unsigned shv[4];         // 0:sel 1:tnext 2:hA0
    __shared__ ull qscr[4];

    // ===== phase A: distributed level-1 reductions =====
    if (bid < 8) {                      // h1 rep-compaction: 2048 bin-jobs
        const int job = bid * BLK + t;
        const int br = job >> 10, bin = job & 1023;
        const uint4* p = (const uint4*)(h1_of(ws, br) + (size_t)bin * REP1);
        unsigned s = 0;
#pragma unroll
        for (int r = 0; r < REP1 / 4; r++) { uint4 q = p[r]; s += q.x + q.y + q.z + q.w; }
        cnt1_of(ws)[job] = s;
    } else if (bid < 16) {              // PN/CEP partial arrays -> Acc
        const int i = (bid - 8) * BLK + t;        // 0..2047, valid < SBT
        ull pv = 0; double a = 0.0, b = 0.0; bool hi = false;
        if (i < SBT) {
            unsigned v = pn_part(ws)[i];
            double2 ce = cep_part(ws)[i];
            pv = (ull)(v & 0xFFFFu) | ((ull)(v >> 16) << 32);
            a = ce.x; b = ce.y; hi = (i >= SB0);
        }
        ull p0 = hi ? 0 : pv, p1 = hi ? pv : 0;
        double a0 = hi ? 0.0 : a, a1 = hi ? a : 0.0;
        double b0 = hi ? 0.0 : b, b1 = hi ? b : 0.0;
        p0 = wred_q(p0); p1 = wred_q(p1);
        a0 = wred_d(a0); a1 = wred_d(a1); b0 = wred_d(b0); b1 = wred_d(b1);
        if ((t & 63) == 0) {
            Acc* A = acc_of(ws);
            if (p0) atomicAdd(&A[0].pn, p0);
            if (p1) atomicAdd(&A[1].pn, p1);
            if (a0 != 0.0) atomicAdd(&A[0].ce0, a0);
            if (a1 != 0.0) atomicAdd(&A[1].ce0, a1);
            if (b0 != 0.0) atomicAdd(&A[0].ce1, b0);
            if (b1 != 0.0) atomicAdd(&A[1].ce1, b1);
        }
    } else if (bid < 32) {              // DM partial array -> Acc
        const int i = (bid - 16) * BLK + t;       // 0..4095, valid < 3200
        double d = 0.0, m = 0.0; bool hi = false;
        if (i < BBLK0 + BBLK1) {
            double2 v = dm_part(ws)[i];
            d = v.x; m = v.y; hi = (i >= BBLK0);
        }
        double d0 = hi ? 0.0 : d, d1 = hi ? d : 0.0;
        double m0 = hi ? 0.0 : m, m1 = hi ? m : 0.0;
        d0 = wred_d(d0); d1 = wred_d(d1); m0 = wred_d(m0); m1 = wred_d(m1);
        if ((t & 63) == 0) {
            Acc* A = acc_of(ws);
            if (d0 != 0.0) atomicAdd(&A[0].d2, d0);
            if (d1 != 0.0) atomicAdd(&A[1].d2, d1);
            if (m0 != 0.0) atomicAdd(&A[0].ms, m0);
            if (m1 != 0.0) atomicAdd(&A[1].ms, m1);
        }
    }
    grid.sync();

    // ===== phase B: level-1 select (block 0 only, on compact data) =====
    if (bid == 0) {
        for (int br = 0; br < 2; br++) {
            BranchCtrl* c = ctrl_of(ws, br);
            Acc* A = acc_of(ws) + br;
            const unsigned N = br ? N1 : N0;
            ull pn = A->pn;
            unsigned P = (unsigned)(pn & 0xFFFFFFFFull);
            unsigned negn = (unsigned)(pn >> 32);
            double CE0 = A->ce0, CE1NN = A->ce1;
            double D = A->d2, M = A->ms;
            const unsigned haspos = (P > 0) ? 1u : 0u;
            unsigned k = haspos ? ((5u * P < negn) ? 5u * P : negn) : (N / 10u);
            unsigned target = (k < 1u) ? 1u : k;
            if (target > N) target = N;

            const unsigned* C1 = cnt1_of(ws) + br * 1024;
            unsigned cnt[2], ssum = 0;
#pragma unroll
            for (int j = 0; j < 2; j++) {
                int i = t * 2 + j;
                unsigned s = C1[i];
                if (i == 0) shv[2] = s;
                if (!haspos) s += C1[512 + i];
                unsigned cv = s + ((haspos && i == 0) ? (N - negn) : 0u);
                cnt[j] = cv; ssum += cv;
            }
            if (t == 0) { shv[0] = 0; shv[1] = 1; }
            __syncthreads();
            pref[t] = ssum;
            __syncthreads();
            for (int off = 1; off < 256; off <<= 1) {
                unsigned x = (t >= off) ? pref[t - off] : 0u;
                __syncthreads();
                pref[t] += x;
                __syncthreads();
            }
            unsigned tot = pref[255];
            if (target > tot) target = tot;
            unsigned before = pref[t] - ssum;
#pragma unroll
            for (int j = 0; j < 2; j++) {
                if (tot && before < target && before + cnt[j] >= target) {
                    shv[0] = (unsigned)(t * 2 + j);
                    shv[1] = target - before;
                }
                before += cnt[j];
            }
            __syncthreads();
            if (t == 0) {
                unsigned sel = shv[0];
                c->pos_num = P; c->neg_num = negn;
                c->ce0 = CE0; c->ce1nn = CE1NN;
                c->loss_bbox = (M > 0.0) ? D / fmax(M, 1e-8) : 0.0;
                if (haspos && sel == 0 && shv[2] == 0) {
                    double cntd = (double)P + (double)(N - negn);
                    if (cntd < 1.0) cntd = 1.0;
                    c->loss_score = (CE0 + CE1NN) / cntd;
                    c->done = 1;
                } else {
                    c->sel1 = sel; c->target = shv[1];
                }
            }
            __syncthreads();
        }
    }
    grid.sync();

    // ===== phase C: refine2 (grid-stride over GRID_R tiles) =====
    for (int vb = bid; vb < GRID_R; vb += nbl) {
        const int br = (vb < RB0) ? 0 : 1;
        const int blk = (vb < RB0) ? vb : vb - RB0;
        if (!ctrl_of(ws, br)->done) {
            unsigned* h = (unsigned*)SMEM;
            for (int i = t; i < 2048; i += BLK) h[i] = 0;
            __syncthreads();
            if (br == 0) refine2_body<0, STORED>(sc0, lb0, ws, blk, h);
            else         refine2_body<1, STORED>(sc1, lb1, ws, blk, h);
            __syncthreads();
            const int rep = vb & (REP2 - 1);
            unsigned* H = h2_of(ws, br);
            for (int i = t; i < 2048; i += BLK) {
                unsigned v = h[i];
                if (v) atomicAdd(&H[(size_t)i * REP2 + rep], v);
            }
        }
        __syncthreads();   // flush reads h before next iteration re-zeroes
    }
    grid.sync();

    // ===== phase D: h2 rep-compaction =====
    if (bid < 16) {
        const int job = bid * BLK + t;            // 0..4095
        const int br = job >> 11, bin = job & 2047;
        const uint4* p = (const uint4*)(h2_of(ws, br) + (size_t)bin * REP2);
        uint4 q0 = p[0], q1 = p[1];
        cnt2_of(ws)[job] = q0.x + q0.y + q0.z + q0.w + q1.x + q1.y + q1.z + q1.w;
    }
    grid.sync();

    // ===== phase E: level-2 select (block 0) =====
    if (bid == 0) {
        for (int br = 0; br < 2; br++) {
            BranchCtrl* c = ctrl_of(ws, br);
            if (c->done) continue;
            unsigned target = c->target;
            const unsigned* C2 = cnt2_of(ws) + br * 2048;
            unsigned cnt[8], ssum = 0;
#pragma unroll
            for (int j = 0; j < 8; j++) { cnt[j] = C2[t * 8 + j]; ssum += cnt[j]; }
            if (t == 0) { shv[0] = 0; shv[1] = 1; }
            __syncthreads();
            pref[t] = ssum;
            __syncthreads();
            for (int off = 1; off < 256; off <<= 1) {
                unsigned x = (t >= off) ? pref[t - off] : 0u;
                __syncthreads();
                pref[t] += x;
                __syncthreads();
            }
            unsigned tot = pref[255];
            if (target > tot) target = tot;
            unsigned before = pref[t] - ssum;
#pragma unroll
            for (int j = 0; j < 8; j++) {
                if (tot && before < target && before + cnt[j] >= target) {
                    shv[0] = (unsigned)(t * 8 + j);
                    shv[1] = target - before;
                }
                before += cnt[j];
            }
            __syncthreads();
            if (t == 0) { c->sel2 = shv[0]; c->target = shv[1]; }
            __syncthreads();
        }
    }
    grid.sync();

    // ===== phase F: refine3 (grid-stride) =====
    for (int vb = bid; vb < GRID_R; vb += nbl) {
        const int br = (vb < RB0) ? 0 : 1;
        const int blk = (vb < RB0) ? vb : vb - RB0;
        if (!ctrl_of(ws, br)->done) {
            ull* h = SMEM;
            for (int i = t; i < 1024; i += BLK) h[i] = 0;
            __syncthreads();
            if (br == 0) refine3_body<0, STORED>(sc0, lb0, ws, blk, vb, h);
            else         refine3_body<1, STORED>(sc1, lb1, ws, blk, vb, h);
        }
        __syncthreads();
    }
    grid.sync();

    // ===== phase G: h3 rep-compaction =====
    if (bid < 8) {
        const int job = bid * BLK + t;            // 0..2047
        const int br = job >> 10, bin = job & 1023;
        const ull* H = h3_of(ws, br) + (size_t)bin * REP2;
        ull e = 0;
#pragma unroll
        for (int r = 0; r < REP2; r++) e += H[r];
        cev_of(ws)[job] = e;
    }
    grid.sync();

    // ===== phase H: level-3 select + finalize (block 0) =====
    if (bid == 0) {
        for (int br = 0; br < 2; br++) {
            BranchCtrl* c = ctrl_of(ws, br);
            if (c->done) continue;
            const unsigned N = br ? N1 : N0;
            unsigned P = c->pos_num, negn = c->neg_num;
            const unsigned haspos = (P > 0) ? 1u : 0u;
            unsigned target = c->target;
            double CE0 = c->ce0, CE1NN = c->ce1nn;
            const ull* CV = cev_of(ws) + br * 1024;
            ull cev[4]; unsigned cnt[4], ssum = 0;
#pragma unroll
            for (int j = 0; j < 4; j++) {
                cev[j] = CV[t * 4 + j];
                cnt[j] = (unsigned)(cev[j] >> 40);
                ssum += cnt[j];
            }
            if (t == 0) { shv[0] = 0; shv[1] = 1; }
            __syncthreads();
            pref[t] = ssum;
            __syncthreads();
            for (int off = 1; off < 256; off <<= 1) {
                unsigned x = (t >= off) ? pref[t - off] : 0u;
                __syncthreads();
                pref[t] += x;
                __syncthreads();
            }
            unsigned tot = pref[255];
            if (target > tot) target = tot;
            unsigned before = pref[t] - ssum;
#pragma unroll
            for (int j = 0; j < 4; j++) {
                if (tot && before < target && before + cnt[j] >= target) {
                    shv[0] = (unsigned)(t * 4 + j);
                    shv[1] = target - before;
                }
                before += cnt[j];
            }
            __syncthreads();
            unsigned sel = shv[0];
            ull cei = 0;
#pragma unroll
            for (int j = 0; j < 4; j++) {
                unsigned bin = (unsigned)(t * 4 + j);
                if (bin <= sel) cei += cev[j];
            }
            cei = wred_q(cei);
            int w = t >> 6;
            if ((t & 63) == 0) qscr[w] = cei;
            __syncthreads();
            if (t == 0) {
                ull CEI = qscr[0] + qscr[1] + qscr[2] + qscr[3];
                const ull* F = fin_of(ws, br);
                ull cl = 0; double cel = 0.0;
                for (int r = 0; r < REP2; r++) {
                    cl += F[r * 2];
                    cel += ((const double*)F)[r * 2 + 1];
                }
                unsigned sel12 = (c->sel1 << 11) | c->sel2;
                double basec = (haspos && sel12 != 0) ? (double)(N - negn) : 0.0;
                double basee = (haspos && sel12 != 0) ? CE1NN : 0.0;
                double cntd = (double)P + basec + (double)cl + (double)(CEI >> 40);
                if (cntd < 1.0) cntd = 1.0;
                double ce = CE0 + basee + cel + (double)(CEI & MASK40) / (double)CE_SCALE;
                c->loss_score = ce / cntd;
            }
            __syncthreads();
        }
        if (t == 0) {
            BranchCtrl* c0 = ctrl_of(ws, 0);
            BranchCtrl* c1 = ctrl_of(ws, 1);
            out[0] = (float)(c0->loss_score + c0->loss_bbox + c1->loss_score + c1->loss_bbox);
            out[1] = (float)c0->loss_score;
            out[2] = (float)c0->loss_bbox;
            out[3] = (float)c1->loss_score;
            out[4] = (float)c1->loss_bbox;
        }
    }
}

// ---------------- host ----------------
template <bool S>
static void run_pipeline(const float4* sc0, const float4* bb0, const float4* mk0, const float4* lb0,
                         const float4* sc1, const float4* bb1, const float4* mk1, const float4* lb1,
                         void* ws, float* out, hipStream_t stream)
{
    pass1<S><<<P1_GRID, BLK, 0, stream>>>(sc0, bb0, mk0, lb0, sc1, bb1, mk1, lb1, ws);

    // grid for cooperative tail: sized from occupancy query, clamped.
    // __launch_bounds__(256,2) + 9.3KB LDS structurally guarantees >=2 blocks/CU.
    static int coopGrid = -1;
    if (coopGrid < 0) {
        int maxB = 0;
        hipError_t qe = hipOccupancyMaxActiveBlocksPerMultiprocessor(
            &maxB, reinterpret_cast<const void*>(&tail_k<S>), BLK, 0);
        if (qe != hipSuccess || maxB < 1) { (void)hipGetLastError(); maxB = 2; }
        if (maxB > 4) maxB = 4;
        long g = (long)maxB * 256;
        if (g > GRID_R) g = GRID_R;
        if (g < 256) g = 256;
        coopGrid = (int)g;
    }

    void* args[6];
    args[0] = (void*)&sc0;
    args[1] = (void*)&lb0;
    args[2] = (void*)&sc1;
    args[3] = (void*)&lb1;
    args[4] = (void*)&ws;
    args[5] = (void*)&out;
    hipError_t err = hipLaunchCooperativeKernel(
        reinterpret_cast<const void*>(&tail_k<S>),
        dim3(coopGrid), dim3(BLK), args, 0, stream);

    if (err != hipSuccess) {
        (void)hipGetLastError();   // clear sticky error, use baseline tail
        scan_pass<<<1, BLK, 0, stream>>>(ws, 1, out);
        refine2_k<S><<<GRID_R, BLK, 0, stream>>>(sc0, lb0, sc1, lb1, ws);
        scan_pass<<<1, BLK, 0, stream>>>(ws, 2, out);
        refine3_k<S><<<GRID_R, BLK, 0, stream>>>(sc0, lb0, sc1, lb1, ws);
        scan_pass<<<1, BLK, 0, stream>>>(ws, 3, out);
    }
}

extern "C" void kernel_launch(void* const* d_in, const int* in_sizes, int n_in,
                              void* d_out, int out_size, void* d_ws, size_t ws_size,
                              hipStream_t stream)
{
    (void)in_sizes; (void)n_in; (void)out_size;
    const float4* sc0 = (const float4*)d_in[0];
    const float4* bb0 = (const float4*)d_in[1];
    const float4* mk0 = (const float4*)d_in[2];
    const float4* lb0 = (const float4*)d_in[3];
    const float4* sc1 = (const float4*)d_in[4];
    const float4* bb1 = (const float4*)d_in[5];
    const float4* mk1 = (const float4*)d_in[6];
    const float4* lb1 = (const float4*)d_in[7];
    float* out = (float*)d_out;

    zero_ws_k<<<(ZERO_V4 + BLK - 1) / BLK, BLK, 0, stream>>>((uint4*)d_ws, ZERO_V4);

    if (ws_size >= WS_NEED)
        run_pipeline<true>(sc0, bb0, mk0, lb0, sc1, bb1, mk1, lb1, d_ws, out, stream);
    else
        run_pipeline<false>(sc0, bb0, mk0, lb0, sc1, bb1, mk1, lb1, d_ws, out, stream);
}

// Round 3
// 323.497 us; speedup vs baseline: 3.1873x; 3.1873x over previous
//
#include <hip/hip_runtime.h>

using ull = unsigned long long;

// ---------------- problem constants ----------------
constexpr int NB  = 32;
constexpr int HW0 = 320 * 320;
constexpr int HW1 = 160 * 160;
constexpr int N0  = NB * HW0;            // 3,276,800
constexpr int N1  = NB * HW1;            // 819,200
constexpr int HW0_4 = HW0 / 4;
constexpr int HW1_4 = HW1 / 4;
constexpr int BLK = 256;

// score blocks: 2 uint4-packs (8 px) per thread -> 512 packs per block
constexpr int SB0 = N0 / 4 / 512;        // 1600
constexpr int SB1 = N1 / 4 / 512;        // 400
constexpr int SBT = SB0 + SB1;           // 2000
// bbox blocks: 5 float4 per stream per thread, fully unrolled
constexpr int BBLK0 = 2560, BBLK1 = 640; // 3,276,800/(2560*256)=5 ; 819,200/(640*256)=5
constexpr int P1_GRID = SBT + BBLK0 + BBLK1;   // 5200
// refine: 4 uint4-packs (16 px) per thread
constexpr int RB0 = 800, RB1 = 200, GRID_R = RB0 + RB1;
constexpr int RT0 = RB0 * BLK;           // 204,800 (uint4 stride)
constexpr int RT1 = RB1 * BLK;           // 51,200

constexpr float CE_SCALE = 16384.0f;
constexpr ull MASK40 = (1ull << 40) - 1;
constexpr int REP1 = 32, REP2 = 8;

// ---------------- workspace layout (bytes) ----------------
constexpr size_t CTRL_OFF = 0;                                   // (reserved)
constexpr size_t ACC_OFF  = 256;                                 // Acc[2] (within zeroed page)
constexpr size_t H1_OFF  = 4096;                                 // u32 [2][1024][REP1] (bin-major)
constexpr size_t H2_OFF  = H1_OFF + (size_t)2 * 1024 * REP1 * 4; // u32 [2][2048][REP2]
constexpr size_t H3_OFF  = H2_OFF + (size_t)2 * 2048 * REP2 * 4; // u64 [2][1024][REP2]
constexpr size_t FIN_OFF = H3_OFF + (size_t)2 * 1024 * REP2 * 8; // [2][REP2][2] u64 cnt, double ce
constexpr size_t ZERO_END = FIN_OFF + 2 * REP2 * 16;             // 528,640
constexpr int    ZERO_V4  = (int)(ZERO_END / 16);                // 33,040 uint4s
constexpr size_t PN_OFF  = ZERO_END;                             // u32[SBT]
constexpr size_t CEP_OFF = PN_OFF + SBT * 4;                     // double2[SBT] (ce0, ce1nn)
constexpr size_t DM_OFF  = CEP_OFF + (size_t)SBT * 16;           // double2[3200] (d2, ms)
// compact reduction outputs (written-before-read each launch; no zeroing needed)
constexpr size_t CN1_OFF = DM_OFF + (size_t)3200 * 16;           // u32[2][1024]
constexpr size_t CN2_OFF = CN1_OFF + (size_t)2 * 1024 * 4;       // u32[2][2048]
constexpr size_t CEV_OFF = CN2_OFF + (size_t)2 * 2048 * 4;       // u64[2][1024] (reserved)
constexpr size_t PB_OFF  = ((CEV_OFF + (size_t)2 * 1024 * 8 + 255) / 256) * 256;
constexpr size_t WS_NEED = PB_OFF + (size_t)(N0 + N1) * 4;       // ~17.05 MB

struct Acc { ull pn; double ce0, ce1, d2, ms; };

__device__ inline Acc*      acc_of(void* ws)       { return (Acc*)((char*)ws + ACC_OFF); }
__device__ inline unsigned* h1_of(void* ws, int br) { return (unsigned*)((char*)ws + H1_OFF) + (size_t)br * 1024 * REP1; }
__device__ inline unsigned* h2_of(void* ws, int br) { return (unsigned*)((char*)ws + H2_OFF) + (size_t)br * 2048 * REP2; }
__device__ inline ull*      h3_of(void* ws, int br) { return (ull*)((char*)ws + H3_OFF) + (size_t)br * 1024 * REP2; }
__device__ inline ull*      fin_of(void* ws, int br) { return (ull*)((char*)ws + FIN_OFF) + (size_t)br * REP2 * 2; }
__device__ inline unsigned* pn_part(void* ws)  { return (unsigned*)((char*)ws + PN_OFF); }
__device__ inline double2*  cep_part(void* ws) { return (double2*)((char*)ws + CEP_OFF); }
__device__ inline double2*  dm_part(void* ws)  { return (double2*)((char*)ws + DM_OFF); }
__device__ inline unsigned* cnt1_of(void* ws)  { return (unsigned*)((char*)ws + CN1_OFF); }
__device__ inline unsigned* cnt2_of(void* ws)  { return (unsigned*)((char*)ws + CN2_OFF); }
__device__ inline unsigned* pb_of(void* ws, int br) { return (unsigned*)((char*)ws + PB_OFF) + (br ? (size_t)N0 : 0); }

// ---------------- reduce helpers ----------------
__device__ __forceinline__ unsigned wred_u(unsigned v) {
#pragma unroll
    for (int o = 32; o > 0; o >>= 1) v += __shfl_down(v, o, 64);
    return v;
}
__device__ __forceinline__ ull wred_q(ull v) {
#pragma unroll
    for (int o = 32; o > 0; o >>= 1) v += __shfl_down(v, o, 64);
    return v;
}
__device__ __forceinline__ double wred_d(double v) {
#pragma unroll
    for (int o = 32; o > 0; o >>= 1) v += __shfl_down(v, o, 64);
    return v;
}

// ---------------- kernels ----------------
__global__ __launch_bounds__(256) void zero_ws_k(uint4* p, int n) {
    int i = blockIdx.x * BLK + threadIdx.x;
    if (i < n) p[i] = make_uint4(0, 0, 0, 0);
}

// ---- pass1 (unchanged from 325 us baseline) ----
template <int BR, bool STORED>
__device__ void score_body(const float4* __restrict__ score, const float4* __restrict__ glabel,
                           void* ws, int blk, int gblk, unsigned* h)
{
    constexpr int HW4 = BR ? HW1_4 : HW0_4;
    const int t = threadIdx.x;
    const int base = blk * 512 + t;

    float4 s0[2], s1[2], g0[2], g1[2];
    int idx[2] = { base, base + 256 };
#pragma unroll
    for (int u = 0; u < 2; u++) {
        int b = idx[u] / HW4, r = idx[u] - b * HW4;
        const float4* sp = score  + (size_t)(b * 2) * HW4 + r;
        const float4* gp = glabel + (size_t)(b * 6) * HW4 + r;
        s0[u] = sp[0]; s1[u] = sp[HW4];
        g0[u] = gp[0]; g1[u] = gp[HW4];
    }

    unsigned posc = 0, negc = 0;
    float ce0 = 0.0f, ce1 = 0.0f;
#pragma unroll
    for (int u = 0; u < 2; u++) {
        uint4 pk;
        unsigned bins[4];
#pragma unroll
        for (int j = 0; j < 4; j++) {
            float a = (&s0[u].x)[j], cc = (&s1[u].x)[j];
            float m = fmaxf(a, cc);
            float e0 = __expf(a - m), e1 = __expf(cc - m);
            float inv = 1.0f / (e0 + e1);
            float p0 = e0 * inv, p1 = e1 * inv;
            float l0 = (&g0[u].x)[j], l1 = (&g1[u].x)[j];
            bool pos = l0 > 0.5f, neg = l1 > 0.5f;
            posc += pos ? 1u : 0u;
            negc += neg ? 1u : 0u;
            if (pos)  ce0 += -l0 * __logf(p0);
            if (!neg) ce1 += -l1 * __logf(p1);
            unsigned pb = __float_as_uint(p1);
            (&pk.x)[j] = pb | (neg ? 0x80000000u : 0u);
            bins[j] = (neg ? 0u : 512u) + (pb >> 21);
        }
        if (STORED) ((uint4*)pb_of(ws, BR))[idx[u]] = pk;
#pragma unroll
        for (int j = 0; j < 4; j++) {
            unsigned bj = bins[j];
            if (bj != 0xFFFFFFFFu) {
                unsigned cnt = 1;
#pragma unroll
                for (int k = j + 1; k < 4; k++)
                    if (bins[k] == bj) { cnt++; bins[k] = 0xFFFFFFFFu; }
                atomicAdd(&h[bj], cnt);
            }
        }
    }

    unsigned pn = posc | (negc << 16);
    pn = wred_u(pn);
    double C0 = wred_d((double)ce0);
    double C1 = wred_d((double)ce1);
    __shared__ unsigned spn[4];
    __shared__ double sc0[4], sc1[4];
    int w = t >> 6, lane = t & 63;
    if (lane == 0) { spn[w] = pn; sc0[w] = C0; sc1[w] = C1; }
    __syncthreads();   // also orders LDS hist atomics before flush
    if (t == 0) {
        pn_part(ws)[gblk] = spn[0] + spn[1] + spn[2] + spn[3];
        cep_part(ws)[gblk] = make_double2(sc0[0] + sc0[1] + sc0[2] + sc0[3],
                                          sc1[0] + sc1[1] + sc1[2] + sc1[3]);
    }
    const int rep = gblk & (REP1 - 1);
    unsigned* H = h1_of(ws, BR);
    for (int i = t; i < 1024; i += BLK) {
        unsigned v = h[i];
        if (v) atomicAdd(&H[(size_t)i * REP1 + rep], v);
    }
}

template <int BR>
__device__ void bbox_body(const float4* __restrict__ bbox, const float4* __restrict__ gmask,
                          const float4* __restrict__ glabel, void* ws, int blk, int gblk)
{
    constexpr int HW4 = BR ? HW1_4 : HW0_4;
    constexpr int NT  = (BR ? BBLK1 : BBLK0) * BLK;
    const int t = threadIdx.x;
    const int i0 = blk * BLK + t;
    float d2 = 0.0f, ms = 0.0f;
#pragma unroll
    for (int k = 0; k < 5; k++) {
        int i = i0 + k * NT;
        int b = i / (4 * HW4);
        int off = i + (2 * b + 2) * HW4;
        float4 pb4 = bbox[i];
        float4 gm  = gmask[off];
        float4 gl  = glabel[off];
#pragma unroll
        for (int j = 0; j < 4; j++) {
            float m = (&gm.x)[j];
            float d = ((&pb4.x)[j] - (&gl.x)[j]) * m;
            d2 += d * d;
            ms += m;
        }
    }
    double D = wred_d((double)d2);
    double M = wred_d((double)ms);
    __shared__ double sdd[4], sdm[4];
    int w = t >> 6, lane = t & 63;
    if (lane == 0) { sdd[w] = D; sdm[w] = M; }
    __syncthreads();
    if (t == 0)
        dm_part(ws)[gblk] = make_double2(sdd[0] + sdd[1] + sdd[2] + sdd[3],
                                         sdm[0] + sdm[1] + sdm[2] + sdm[3]);
}

template <bool STORED>
__global__ __launch_bounds__(256, 4) void pass1(
    const float4* __restrict__ sc0, const float4* __restrict__ bb0,
    const float4* __restrict__ mk0, const float4* __restrict__ lb0,
    const float4* __restrict__ sc1, const float4* __restrict__ bb1,
    const float4* __restrict__ mk1, const float4* __restrict__ lb1,
    void* ws)
{
    __shared__ unsigned h[1024];
    const int bid = blockIdx.x;
    if (bid < SBT) {
        for (int i = threadIdx.x; i < 1024; i += BLK) h[i] = 0;
        __syncthreads();
        if (bid < SB0) score_body<0, STORED>(sc0, lb0, ws, bid, bid, h);
        else           score_body<1, STORED>(sc1, lb1, ws, bid - SB0, bid, h);
    } else if (bid < SBT + BBLK0) {
        bbox_body<0>(bb0, mk0, lb0, ws, bid - SBT, bid - SBT);
    } else {
        bbox_body<1>(bb1, mk1, lb1, ws, bid - SBT - BBLK0, bid - SBT);
    }
}

// ---------------- redundant per-block selects ----------------
// All inputs (PN, h1, h2, cnt1, cnt2, Acc.pn) are finalized integers at the
// preceding kernel boundary, so every block computes the SAME result.

struct Sel1R { unsigned P, negn, haspos, sel1, tnext, done, hA0; };

// shared scratch: pref[256], shv[4], shq[4]
__device__ void sel1_common(int br, unsigned P, unsigned negn, const unsigned* C1raw,
                            bool rawRep, Sel1R& R, unsigned* pref, unsigned* shv)
{
    const int t = threadIdx.x;
    const unsigned N = br ? N1 : N0;
    const unsigned haspos = (P > 0) ? 1u : 0u;
    unsigned k = haspos ? ((5u * P < negn) ? 5u * P : negn) : (N / 10u);
    unsigned target = (k < 1u) ? 1u : k;
    if (target > N) target = N;

    unsigned cnt[2], ssum = 0;
#pragma unroll
    for (int j = 0; j < 2; j++) {
        int i = t * 2 + j;
        unsigned s;
        if (rawRep) {
            const uint4* p = (const uint4*)(C1raw + (size_t)i * REP1);
            s = 0;
#pragma unroll
            for (int r = 0; r < REP1 / 4; r++) { uint4 q = p[r]; s += q.x + q.y + q.z + q.w; }
        } else {
            s = C1raw[i];
        }
        if (i == 0) shv[2] = s;
        if (!haspos) {
            if (rawRep) {
                const uint4* p2 = (const uint4*)(C1raw + (size_t)(512 + i) * REP1);
#pragma unroll
                for (int r = 0; r < REP1 / 4; r++) { uint4 q = p2[r]; s += q.x + q.y + q.z + q.w; }
            } else {
                s += C1raw[512 + i];
            }
        }
        unsigned cv = s + ((haspos && i == 0) ? (N - negn) : 0u);
        cnt[j] = cv; ssum += cv;
    }
    if (t == 0) { shv[0] = 0; shv[1] = 1; }
    __syncthreads();
    pref[t] = ssum;
    __syncthreads();
    for (int off = 1; off < 256; off <<= 1) {
        unsigned x = (t >= off) ? pref[t - off] : 0u;
        __syncthreads();
        pref[t] += x;
        __syncthreads();
    }
    unsigned tot = pref[255];
    if (target > tot) target = tot;
    unsigned before = pref[t] - ssum;
#pragma unroll
    for (int j = 0; j < 2; j++) {
        if (tot && before < target && before + cnt[j] >= target) {
            shv[0] = (unsigned)(t * 2 + j);
            shv[1] = target - before;
        }
        before += cnt[j];
    }
    __syncthreads();
    R.P = P; R.negn = negn; R.haspos = haspos;
    R.sel1 = shv[0]; R.tnext = shv[1]; R.hA0 = shv[2];
    R.done = (haspos && R.sel1 == 0 && R.hA0 == 0) ? 1u : 0u;
    __syncthreads();   // protect shv/pref reuse by caller
}

// version used by refine2': raw PN + raw h1
__device__ void compute_sel1_raw(void* ws, int br, Sel1R& R,
                                 unsigned* pref, unsigned* shv, ull* shq)
{
    const int t = threadIdx.x;
    const unsigned* PN = pn_part(ws);
    const int lo = br ? SB0 : 0, hi = br ? SBT : SB0;
    ull pn = 0;
    for (int i = lo + t; i < hi; i += BLK) {
        unsigned v = PN[i];
        pn += (ull)(v & 0xFFFFu) | ((ull)(v >> 16) << 32);
    }
    pn = wred_q(pn);
    int w = t >> 6;
    if ((t & 63) == 0) shq[w] = pn;
    __syncthreads();
    ull tot = shq[0] + shq[1] + shq[2] + shq[3];
    unsigned P = (unsigned)(tot & 0xFFFFFFFFull);
    unsigned negn = (unsigned)(tot >> 32);
    __syncthreads();
    sel1_common(br, P, negn, h1_of(ws, br), true, R, pref, shv);
}

// version used by refine3'/scan_final: Acc.pn + compact cnt1
__device__ void compute_sel1_compact(void* ws, int br, Sel1R& R,
                                     unsigned* pref, unsigned* shv)
{
    ull pn = acc_of(ws)[br].pn;
    unsigned P = (unsigned)(pn & 0xFFFFFFFFull);
    unsigned negn = (unsigned)(pn >> 32);
    sel1_common(br, P, negn, cnt1_of(ws) + (size_t)br * 1024, false, R, pref, shv);
}

// level-2 select; C2raw either raw h2 (rep-major, rawRep) or compact cnt2
__device__ void compute_sel2(const unsigned* C2raw, bool rawRep, unsigned target,
                             unsigned& sel2, unsigned& tnext, unsigned* pref, unsigned* shv)
{
    const int t = threadIdx.x;
    unsigned cnt[8], ssum = 0;
#pragma unroll
    for (int j = 0; j < 8; j++) {
        int i = t * 8 + j;
        unsigned s;
        if (rawRep) {
            const uint4* p = (const uint4*)(C2raw + (size_t)i * REP2);
            uint4 q0 = p[0], q1 = p[1];
            s = q0.x + q0.y + q0.z + q0.w + q1.x + q1.y + q1.z + q1.w;
        } else {
            s = C2raw[i];
        }
        cnt[j] = s; ssum += s;
    }
    if (t == 0) { shv[0] = 0; shv[1] = 1; }
    __syncthreads();
    pref[t] = ssum;
    __syncthreads();
    for (int off = 1; off < 256; off <<= 1) {
        unsigned x = (t >= off) ? pref[t - off] : 0u;
        __syncthreads();
        pref[t] += x;
        __syncthreads();
    }
    unsigned tot = pref[255];
    if (target > tot) target = tot;
    unsigned before = pref[t] - ssum;
#pragma unroll
    for (int j = 0; j < 8; j++) {
        if (tot && before < target && before + cnt[j] >= target) {
            shv[0] = (unsigned)(t * 8 + j);
            shv[1] = target - before;
        }
        before += cnt[j];
    }
    __syncthreads();
    sel2 = shv[0]; tnext = shv[1];
    __syncthreads();
}

// ---- refine2 body (ctrl reads replaced by params) ----
template <int BR, bool STORED>
__device__ void refine2_body(const float4* __restrict__ score, const float4* __restrict__ glabel,
                             void* ws, int blk, unsigned* h, unsigned haspos, unsigned sel1)
{
    constexpr int T = BR ? RT1 : RT0;
    constexpr int HW4 = BR ? HW1_4 : HW0_4;
    const int base = blk * BLK + (int)threadIdx.x;

    unsigned pk[16];
    if (STORED) {
        const uint4* pb4 = (const uint4*)pb_of(ws, BR);
#pragma unroll
        for (int i = 0; i < 4; i++) {
            uint4 q = pb4[base + i * T];
            pk[i*4+0]=q.x; pk[i*4+1]=q.y; pk[i*4+2]=q.z; pk[i*4+3]=q.w;
        }
    } else {
#pragma unroll
        for (int i = 0; i < 4; i++) {
            int id = base + i * T;
            int b = id / HW4, r = id - b * HW4;
            float4 s0 = score[(size_t)(b*2)*HW4 + r];
            float4 s1 = score[(size_t)(b*2+1)*HW4 + r];
            float4 g1 = glabel[(size_t)(b*6+1)*HW4 + r];
#pragma unroll
            for (int j = 0; j < 4; j++) {
                float a=(&s0.x)[j], cc=(&s1.x)[j];
                float m=fmaxf(a,cc);
                float e0=__expf(a-m), e1=__expf(cc-m);
                float p1=e1/(e0+e1);
                pk[i*4+j] = __float_as_uint(p1) | (((&g1.x)[j] > 0.5f) ? 0x80000000u : 0u);
            }
        }
    }
    unsigned z = 0;
#pragma unroll
    for (int i = 0; i < 4; i++) {
        unsigned bins[4];
#pragma unroll
        for (int j = 0; j < 4; j++) {
            unsigned raw = pk[i*4+j], pbv = raw & 0x7FFFFFFFu;
            unsigned npb = haspos ? ((raw >> 31) ? pbv : 0u) : pbv;
            bool m = (npb >> 21) == sel1;
            if (m && npb == 0) { z++; bins[j] = 0xFFFFFFFFu; }
            else bins[j] = m ? ((npb >> 10) & 0x7FFu) : 0xFFFFFFFFu;
        }
#pragma unroll
        for (int j = 0; j < 4; j++) {
            unsigned bj = bins[j];
            if (bj != 0xFFFFFFFFu) {
                unsigned cnt = 1;
#pragma unroll
                for (int k = j + 1; k < 4; k++)
                    if (bins[k] == bj) { cnt++; bins[k] = 0xFFFFFFFFu; }
                atomicAdd(&h[bj], cnt);
            }
        }
    }
    if (z) atomicAdd(&h[0], z);
}

// ---- refine3 body (ctrl reads replaced by params) ----
template <int BR, bool STORED>
__device__ void refine3_body(const float4* __restrict__ score, const float4* __restrict__ glabel,
                             void* ws, int blk, int gblk, ull* h,
                             unsigned haspos, unsigned sel1, unsigned sel2)
{
    const unsigned sel12 = (sel1 << 11) | sel2;
    constexpr int T = BR ? RT1 : RT0;
    constexpr int HW4 = BR ? HW1_4 : HW0_4;
    constexpr int HW  = BR ? HW1 : HW0;
    const int base = blk * BLK + (int)threadIdx.x;
    const float* glab_s = (const float*)glabel;

    unsigned pk[16];
    float g1v[16];
    if (STORED) {
        const uint4* pb4 = (const uint4*)pb_of(ws, BR);
#pragma unroll
        for (int i = 0; i < 4; i++) {
            uint4 q = pb4[base + i * T];
            pk[i*4+0]=q.x; pk[i*4+1]=q.y; pk[i*4+2]=q.z; pk[i*4+3]=q.w;
        }
    } else {
#pragma unroll
        for (int i = 0; i < 4; i++) {
            int id = base + i * T;
            int b = id / HW4, r = id - b * HW4;
            float4 s0 = score[(size_t)(b*2)*HW4 + r];
            float4 s1 = score[(size_t)(b*2+1)*HW4 + r];
            float4 g1 = glabel[(size_t)(b*6+1)*HW4 + r];
#pragma unroll
            for (int j = 0; j < 4; j++) {
                float a=(&s0.x)[j], cc=(&s1.x)[j];
                float m=fmaxf(a,cc);
                float e0=__expf(a-m), e1=__expf(cc-m);
                float p1=e1/(e0+e1);
                pk[i*4+j] = __float_as_uint(p1) | (((&g1.x)[j] > 0.5f) ? 0x80000000u : 0u);
                g1v[i*4+j] = (&g1.x)[j];
            }
        }
    }

    ull cnt_lt = 0;
    double ce_lt = 0.0;
    ull zpack = 0;
#pragma unroll
    for (int i = 0; i < 4; i++) {
#pragma unroll
        for (int j = 0; j < 4; j++) {
            unsigned raw = pk[i*4+j], pbv = raw & 0x7FFFFFFFu;
            unsigned npb = haspos ? ((raw >> 31) ? pbv : 0u) : pbv;
            bool iszero = (npb == 0);
            if (iszero && sel12 != 0) continue;  // accounted via base in scan_final
            unsigned b1 = npb >> 21, b2 = (npb >> 10) & 0x7FFu;
            bool lt = (b1 < sel1) || (b1 == sel1 && b2 < sel2);
            bool eq = ((npb >> 10) == sel12);
            if (lt || eq) {
                float g1s;
                if (STORED) {
                    int px = (base + i * T) * 4 + j;
                    int bb = px / HW, rr = px - bb * HW;
                    g1s = glab_s[(size_t)(bb * 6 + 1) * HW + rr];
                } else {
                    g1s = g1v[i*4+j];
                }
                float ce = -g1s * __logf(__uint_as_float(pbv));
                if (lt) { cnt_lt++; ce_lt += (double)ce; }
                else {
                    ull v = (1ull << 40) | (ull)__float2uint_rn(ce * CE_SCALE);
                    if (iszero) zpack += v;
                    else atomicAdd(&h[npb & 0x3FFu], v);
                }
            }
        }
    }
    if (zpack) atomicAdd(&h[0], zpack);

    ull CL = wred_q(cnt_lt);
    double CE = wred_d(ce_lt);
    __shared__ ull sq[4];
    __shared__ double sd[4];
    int t = threadIdx.x, w = t >> 6, lane = t & 63;
    if (lane == 0) { sq[w] = CL; sd[w] = CE; }
    __syncthreads();   // also orders LDS hist atomics before flush
    if (t == 0) {
        ull totc = sq[0] + sq[1] + sq[2] + sq[3];
        double totd = sd[0] + sd[1] + sd[2] + sd[3];
        ull* F = fin_of(ws, BR) + (size_t)(gblk & (REP2 - 1)) * 2;
        if (totc) atomicAdd(&F[0], totc);
        if (totd != 0.0) atomicAdd((double*)&F[1], totd);
    }
    const int rep = gblk & (REP2 - 1);
    ull* H = h3_of(ws, BR);
    for (int i = t; i < 1024; i += BLK) {
        ull v = h[i];
        if (v) atomicAdd(&H[(size_t)i * REP2 + rep], v);
    }
}

// ---- refine2': spare compaction duties + per-block select1 + tile work ----
template <bool STORED>
__global__ __launch_bounds__(256) void refine2_k2(
    const float4* __restrict__ sc0, const float4* __restrict__ lb0,
    const float4* __restrict__ sc1, const float4* __restrict__ lb1, void* ws)
{
    __shared__ unsigned h[2048];
    __shared__ unsigned pref[256];
    __shared__ unsigned shv[4];
    __shared__ ull shq[4];
    const int t = threadIdx.x;
    const int bid = blockIdx.x;

    // spare duties: compact h1 -> cnt1; reduce PN/CEP -> Acc; reduce DM -> Acc.
    // These run unconditionally (needed even if a branch turns out done).
    if (bid < 8) {
        const int job = bid * BLK + t;            // 0..2047
        const int jbr = job >> 10, bin = job & 1023;
        const uint4* p = (const uint4*)(h1_of(ws, jbr) + (size_t)bin * REP1);
        unsigned s = 0;
#pragma unroll
        for (int r = 0; r < REP1 / 4; r++) { uint4 q = p[r]; s += q.x + q.y + q.z + q.w; }
        cnt1_of(ws)[job] = s;
    } else if (bid < 16) {
        const int i = (bid - 8) * BLK + t;        // 0..2047, valid < SBT
        ull pv = 0; double a = 0.0, b = 0.0; bool hi = false;
        if (i < SBT) {
            unsigned v = pn_part(ws)[i];
            double2 ce = cep_part(ws)[i];
            pv = (ull)(v & 0xFFFFu) | ((ull)(v >> 16) << 32);
            a = ce.x; b = ce.y; hi = (i >= SB0);
        }
        ull p0 = hi ? 0 : pv, p1 = hi ? pv : 0;
        double a0 = hi ? 0.0 : a, a1 = hi ? a : 0.0;
        double b0 = hi ? 0.0 : b, b1 = hi ? b : 0.0;
        p0 = wred_q(p0); p1 = wred_q(p1);
        a0 = wred_d(a0); a1 = wred_d(a1); b0 = wred_d(b0); b1 = wred_d(b1);
        if ((t & 63) == 0) {
            Acc* A = acc_of(ws);
            if (p0) atomicAdd(&A[0].pn, p0);
            if (p1) atomicAdd(&A[1].pn, p1);
            if (a0 != 0.0) atomicAdd(&A[0].ce0, a0);
            if (a1 != 0.0) atomicAdd(&A[1].ce0, a1);
            if (b0 != 0.0) atomicAdd(&A[0].ce1, b0);
            if (b1 != 0.0) atomicAdd(&A[1].ce1, b1);
        }
    } else if (bid < 32) {
        const int i = (bid - 16) * BLK + t;       // 0..4095, valid < 3200
        double d = 0.0, m = 0.0; bool hi = false;
        if (i < BBLK0 + BBLK1) {
            double2 v = dm_part(ws)[i];
            d = v.x; m = v.y; hi = (i >= BBLK0);
        }
        double d0 = hi ? 0.0 : d, d1 = hi ? d : 0.0;
        double m0 = hi ? 0.0 : m, m1 = hi ? m : 0.0;
        d0 = wred_d(d0); d1 = wred_d(d1); m0 = wred_d(m0); m1 = wred_d(m1);
        if ((t & 63) == 0) {
            Acc* A = acc_of(ws);
            if (d0 != 0.0) atomicAdd(&A[0].d2, d0);
            if (d1 != 0.0) atomicAdd(&A[1].d2, d1);
            if (m0 != 0.0) atomicAdd(&A[0].ms, m0);
            if (m1 != 0.0) atomicAdd(&A[1].ms, m1);
        }
    }

    const int br  = (bid < RB0) ? 0 : 1;
    const int blk = (bid < RB0) ? bid : bid - RB0;

    Sel1R s1;
    compute_sel1_raw(ws, br, s1, pref, shv, shq);
    if (s1.done) return;

    for (int i = t; i < 2048; i += BLK) h[i] = 0;
    __syncthreads();
    if (br == 0) refine2_body<0, STORED>(sc0, lb0, ws, blk, h, s1.haspos, s1.sel1);
    else         refine2_body<1, STORED>(sc1, lb1, ws, blk, h, s1.haspos, s1.sel1);
    __syncthreads();
    const int rep = bid & (REP2 - 1);
    unsigned* H = h2_of(ws, br);
    for (int i = t; i < 2048; i += BLK) {
        unsigned v = h[i];
        if (v) atomicAdd(&H[(size_t)i * REP2 + rep], v);
    }
}

// ---- refine3': spare h2 compaction + per-block select1 (compact) + select2 (raw h2) + tile ----
template <bool STORED>
__global__ __launch_bounds__(256) void refine3_k2(
    const float4* __restrict__ sc0, const float4* __restrict__ lb0,
    const float4* __restrict__ sc1, const float4* __restrict__ lb1, void* ws)
{
    __shared__ ull h[1024];
    __shared__ unsigned pref[256];
    __shared__ unsigned shv[4];
    const int t = threadIdx.x;
    const int bid = blockIdx.x;

    // spare duty: compact h2 -> cnt2 (for scan_final)
    if (bid < 16) {
        const int job = bid * BLK + t;            // 0..4095
        const int jbr = job >> 11, bin = job & 2047;
        const uint4* p = (const uint4*)(h2_of(ws, jbr) + (size_t)bin * REP2);
        uint4 q0 = p[0], q1 = p[1];
        cnt2_of(ws)[job] = q0.x + q0.y + q0.z + q0.w + q1.x + q1.y + q1.z + q1.w;
    }

    const int br  = (bid < RB0) ? 0 : 1;
    const int blk = (bid < RB0) ? bid : bid - RB0;

    Sel1R s1;
    compute_sel1_compact(ws, br, s1, pref, shv);
    if (s1.done) return;

    unsigned sel2, tnx2;
    compute_sel2(h2_of(ws, br), true, s1.tnext, sel2, tnx2, pref, shv);

    for (int i = t; i < 1024; i += BLK) h[i] = 0;
    __syncthreads();
    if (br == 0) refine3_body<0, STORED>(sc0, lb0, ws, blk, bid, h, s1.haspos, s1.sel1, sel2);
    else         refine3_body<1, STORED>(sc1, lb1, ws, blk, bid, h, s1.haspos, s1.sel1, sel2);
}

// ---- scan_final: single small block on compact data + h3/fin ----
__global__ __launch_bounds__(256) void scan_final(void* ws, float* out)
{
    const int t = threadIdx.x;
    __shared__ unsigned pref[256];
    __shared__ unsigned shv[4];
    __shared__ ull qscr[4];
    __shared__ double sls[2], slb[2];

    for (int br = 0; br < 2; br++) {
        const unsigned N = br ? N1 : N0;
        Acc* A = acc_of(ws) + br;
        ull pn = A->pn;
        unsigned P = (unsigned)(pn & 0xFFFFFFFFull);
        unsigned negn = (unsigned)(pn >> 32);
        double CE0 = A->ce0, CE1NN = A->ce1;
        double D = A->d2, M = A->ms;
        double lb = (M > 0.0) ? D / fmax(M, 1e-8) : 0.0;

        Sel1R s1;
        compute_sel1_compact(ws, br, s1, pref, shv);

        if (s1.done) {
            if (t == 0) {
                double cntd = (double)P + (double)(N - negn);
                if (cntd < 1.0) cntd = 1.0;
                sls[br] = (CE0 + CE1NN) / cntd;
                slb[br] = lb;
            }
            __syncthreads();
            continue;
        }

        unsigned sel2, tnx2;
        compute_sel2(cnt2_of(ws) + (size_t)br * 2048, false, s1.tnext, sel2, tnx2, pref, shv);

        // level-3 select on h3 (reduce REP2 inline)
        const ull* H3 = h3_of(ws, br);
        ull cev[4]; unsigned cnt[4], ssum = 0;
#pragma unroll
        for (int j = 0; j < 4; j++) {
            int i = t * 4 + j;
            ull e = 0;
#pragma unroll
            for (int r = 0; r < REP2; r++) e += H3[(size_t)i * REP2 + r];
            cev[j] = e;
            cnt[j] = (unsigned)(e >> 40);
            ssum += cnt[j];
        }
        unsigned target = tnx2;
        if (t == 0) { shv[0] = 0; shv[1] = 1; }
        __syncthreads();
        pref[t] = ssum;
        __syncthreads();
        for (int off = 1; off < 256; off <<= 1) {
            unsigned x = (t >= off) ? pref[t - off] : 0u;
            __syncthreads();
            pref[t] += x;
            __syncthreads();
        }
        unsigned tot = pref[255];
        if (target > tot) target = tot;
        unsigned before = pref[t] - ssum;
#pragma unroll
        for (int j = 0; j < 4; j++) {
            if (tot && before < target && before + cnt[j] >= target) {
                shv[0] = (unsigned)(t * 4 + j);
                shv[1] = target - before;
            }
            before += cnt[j];
        }
        __syncthreads();
        unsigned sel3 = shv[0];

        ull cei = 0;
#pragma unroll
        for (int j = 0; j < 4; j++) {
            unsigned bin = (unsigned)(t * 4 + j);
            if (bin <= sel3) cei += cev[j];
        }
        cei = wred_q(cei);
        int w = t >> 6;
        if ((t & 63) == 0) qscr[w] = cei;
        __syncthreads();
        if (t == 0) {
            ull CEI = qscr[0] + qscr[1] + qscr[2] + qscr[3];
            const ull* F = fin_of(ws, br);
            ull cl = 0; double cel = 0.0;
            for (int r = 0; r < REP2; r++) {
                cl += F[r * 2];
                cel += ((const double*)F)[r * 2 + 1];
            }
            unsigned sel12 = (s1.sel1 << 11) | sel2;
            double basec = (s1.haspos && sel12 != 0) ? (double)(N - negn) : 0.0;
            double basee = (s1.haspos && sel12 != 0) ? CE1NN : 0.0;
            double cntd = (double)P + basec + (double)cl + (double)(CEI >> 40);
            if (cntd < 1.0) cntd = 1.0;
            double ce = CE0 + basee + cel + (double)(CEI & MASK40) / (double)CE_SCALE;
            sls[br] = ce / cntd;
            slb[br] = lb;
        }
        __syncthreads();
    }

    if (t == 0) {
        out[0] = (float)(sls[0] + slb[0] + sls[1] + slb[1]);
        out[1] = (float)sls[0];
        out[2] = (float)slb[0];
        out[3] = (float)sls[1];
        out[4] = (float)slb[1];
    }
}

// ---------------- host ----------------
template <bool S>
static void run_pipeline(const float4* sc0, const float4* bb0, const float4* mk0, const float4* lb0,
                         const float4* sc1, const float4* bb1, const float4* mk1, const float4* lb1,
                         void* ws, float* out, hipStream_t stream)
{
    pass1<S><<<P1_GRID, BLK, 0, stream>>>(sc0, bb0, mk0, lb0, sc1, bb1, mk1, lb1, ws);
    refine2_k2<S><<<GRID_R, BLK, 0, stream>>>(sc0, lb0, sc1, lb1, ws);
    refine3_k2<S><<<GRID_R, BLK, 0, stream>>>(sc0, lb0, sc1, lb1, ws);
    scan_final<<<1, BLK, 0, stream>>>(ws, out);
}

extern "C" void kernel_launch(void* const* d_in, const int* in_sizes, int n_in,
                              void* d_out, int out_size, void* d_ws, size_t ws_size,
                              hipStream_t stream)
{
    (void)in_sizes; (void)n_in; (void)out_size;
    const float4* sc0 = (const float4*)d_in[0];
    const float4* bb0 = (const float4*)d_in[1];
    const float4* mk0 = (const float4*)d_in[2];
    const float4* lb0 = (const float4*)d_in[3];
    const float4* sc1 = (const float4*)d_in[4];
    const float4* bb1 = (const float4*)d_in[5];
    const float4* mk1 = (const float4*)d_in[6];
    const float4* lb1 = (const float4*)d_in[7];
    float* out = (float*)d_out;

    zero_ws_k<<<(ZERO_V4 + BLK - 1) / BLK, BLK, 0, stream>>>((uint4*)d_ws, ZERO_V4);

    if (ws_size >= WS_NEED)
        run_pipeline<true>(sc0, bb0, mk0, lb0, sc1, bb1, mk1, lb1, d_ws, out, stream);
    else
        run_pipeline<false>(sc0, bb0, mk0, lb0, sc1, bb1, mk1, lb1, d_ws, out, stream);
}

// Round 5
// 311.284 us; speedup vs baseline: 3.3124x; 1.0392x over previous
//
#include <hip/hip_runtime.h>

using ull = unsigned long long;

#if defined(__has_builtin)
#  if __has_builtin(__builtin_amdgcn_sched_barrier)
#    define SCHED_FENCE() __builtin_amdgcn_sched_barrier(0)
#  else
#    define SCHED_FENCE() do {} while (0)
#  endif
#else
#  define SCHED_FENCE() do {} while (0)
#endif

// ---------------- problem constants ----------------
constexpr int NB  = 32;
constexpr int HW0 = 320 * 320;
constexpr int HW1 = 160 * 160;
constexpr int N0  = NB * HW0;            // 3,276,800
constexpr int N1  = NB * HW1;            // 819,200
constexpr int HW0_4 = HW0 / 4;
constexpr int HW1_4 = HW1 / 4;
constexpr int BLK = 256;

// score blocks: 4 uint4-packs (16 px) per thread -> 1024 packs per block
constexpr int SB0 = N0 / 4 / 1024;       // 800
constexpr int SB1 = N1 / 4 / 1024;       // 200
constexpr int SBT = SB0 + SB1;           // 1000
// bbox blocks: 5 float4 per stream per thread, fully unrolled
constexpr int BBLK0 = 2560, BBLK1 = 640; // 3,276,800/(2560*256)=5 ; 819,200/(640*256)=5
constexpr int P1_GRID = SBT + BBLK0 + BBLK1;   // 4200
// refine: 4 uint4-packs (16 px) per thread
constexpr int RB0 = 800, RB1 = 200, GRID_R = RB0 + RB1;
constexpr int RT0 = RB0 * BLK;           // 204,800 (uint4 stride)
constexpr int RT1 = RB1 * BLK;           // 51,200

constexpr float CE_SCALE = 16384.0f;
constexpr ull MASK40 = (1ull << 40) - 1;
constexpr int REP1 = 32, REP2 = 8;

// ---------------- workspace layout (bytes) ----------------
constexpr size_t CTRL_OFF = 0;                                   // (reserved)
constexpr size_t ACC_OFF  = 256;                                 // Acc[2] (within zeroed page)
constexpr size_t H1_OFF  = 4096;                                 // u32 [2][1024][REP1] (bin-major)
constexpr size_t H2_OFF  = H1_OFF + (size_t)2 * 1024 * REP1 * 4; // u32 [2][2048][REP2]
constexpr size_t H3_OFF  = H2_OFF + (size_t)2 * 2048 * REP2 * 4; // u64 [2][1024][REP2]
constexpr size_t FIN_OFF = H3_OFF + (size_t)2 * 1024 * REP2 * 8; // [2][REP2][2] u64 cnt, double ce
constexpr size_t ZERO_END = FIN_OFF + 2 * REP2 * 16;             // 528,640
constexpr int    ZERO_V4  = (int)(ZERO_END / 16);                // 33,040 uint4s
constexpr size_t PN_OFF  = ZERO_END;                             // u32[SBT]
constexpr size_t CEP_OFF = PN_OFF + SBT * 4;                     // double2[SBT] (ce0, ce1nn)
constexpr size_t DM_OFF  = CEP_OFF + (size_t)SBT * 16;           // double2[3200] (d2, ms)
// compact reduction outputs (written-before-read each launch; no zeroing needed)
constexpr size_t CN1_OFF = DM_OFF + (size_t)3200 * 16;           // u32[2][1024]
constexpr size_t CN2_OFF = CN1_OFF + (size_t)2 * 1024 * 4;       // u32[2][2048]
constexpr size_t CEV_OFF = CN2_OFF + (size_t)2 * 2048 * 4;       // u64[2][1024] (reserved)
constexpr size_t PB_OFF  = ((CEV_OFF + (size_t)2 * 1024 * 8 + 255) / 256) * 256;
constexpr size_t WS_NEED = PB_OFF + (size_t)(N0 + N1) * 4;       // ~17.05 MB

struct Acc { ull pn; double ce0, ce1, d2, ms; };

__device__ inline Acc*      acc_of(void* ws)       { return (Acc*)((char*)ws + ACC_OFF); }
__device__ inline unsigned* h1_of(void* ws, int br) { return (unsigned*)((char*)ws + H1_OFF) + (size_t)br * 1024 * REP1; }
__device__ inline unsigned* h2_of(void* ws, int br) { return (unsigned*)((char*)ws + H2_OFF) + (size_t)br * 2048 * REP2; }
__device__ inline ull*      h3_of(void* ws, int br) { return (ull*)((char*)ws + H3_OFF) + (size_t)br * 1024 * REP2; }
__device__ inline ull*      fin_of(void* ws, int br) { return (ull*)((char*)ws + FIN_OFF) + (size_t)br * REP2 * 2; }
__device__ inline unsigned* pn_part(void* ws)  { return (unsigned*)((char*)ws + PN_OFF); }
__device__ inline double2*  cep_part(void* ws) { return (double2*)((char*)ws + CEP_OFF); }
__device__ inline double2*  dm_part(void* ws)  { return (double2*)((char*)ws + DM_OFF); }
__device__ inline unsigned* cnt1_of(void* ws)  { return (unsigned*)((char*)ws + CN1_OFF); }
__device__ inline unsigned* cnt2_of(void* ws)  { return (unsigned*)((char*)ws + CN2_OFF); }
__device__ inline unsigned* pb_of(void* ws, int br) { return (unsigned*)((char*)ws + PB_OFF) + (br ? (size_t)N0 : 0); }

// ---------------- reduce helpers ----------------
__device__ __forceinline__ unsigned wred_u(unsigned v) {
#pragma unroll
    for (int o = 32; o > 0; o >>= 1) v += __shfl_down(v, o, 64);
    return v;
}
__device__ __forceinline__ ull wred_q(ull v) {
#pragma unroll
    for (int o = 32; o > 0; o >>= 1) v += __shfl_down(v, o, 64);
    return v;
}
__device__ __forceinline__ double wred_d(double v) {
#pragma unroll
    for (int o = 32; o > 0; o >>= 1) v += __shfl_down(v, o, 64);
    return v;
}

// ---------------- kernels ----------------
__global__ __launch_bounds__(256) void zero_ws_k(uint4* p, int n) {
    int i = blockIdx.x * BLK + threadIdx.x;
    if (i < n) p[i] = make_uint4(0, 0, 0, 0);
}

// ---- pass1: MLP-restructured (all loads issued before compute; 16 px/thread score) ----
template <int BR, bool STORED>
__device__ void score_body(const float4* __restrict__ score, const float4* __restrict__ glabel,
                           void* ws, int blk, int gblk, unsigned* h)
{
    constexpr int HW4 = BR ? HW1_4 : HW0_4;
    const int t = threadIdx.x;
    const int base = blk * 1024 + t;

    float4 s0[4], s1[4], g0[4], g1[4];
    int idx[4];
#pragma unroll
    for (int u = 0; u < 4; u++) {
        idx[u] = base + 256 * u;
        int b = idx[u] / HW4, r = idx[u] - b * HW4;
        const float4* sp = score  + (size_t)(b * 2) * HW4 + r;
        const float4* gp = glabel + (size_t)(b * 6) * HW4 + r;
        s0[u] = sp[0]; s1[u] = sp[HW4];
        g0[u] = gp[0]; g1[u] = gp[HW4];
    }
    SCHED_FENCE();   // all 16 loads issued before compute

    unsigned posc = 0, negc = 0;
    double ce0d = 0.0, ce1d = 0.0;
#pragma unroll
    for (int u = 0; u < 4; u++) {
        uint4 pk;
        unsigned bins[4];
        float c0 = 0.0f, c1 = 0.0f;
#pragma unroll
        for (int j = 0; j < 4; j++) {
            float a = (&s0[u].x)[j], cc = (&s1[u].x)[j];
            float m = fmaxf(a, cc);
            float e0 = __expf(a - m), e1 = __expf(cc - m);
            float inv = 1.0f / (e0 + e1);
            float p0 = e0 * inv, p1 = e1 * inv;
            float l0 = (&g0[u].x)[j], l1 = (&g1[u].x)[j];
            bool pos = l0 > 0.5f, neg = l1 > 0.5f;
            posc += pos ? 1u : 0u;
            negc += neg ? 1u : 0u;
            if (pos)  c0 += -l0 * __logf(p0);
            if (!neg) c1 += -l1 * __logf(p1);
            unsigned pb = __float_as_uint(p1);
            (&pk.x)[j] = pb | (neg ? 0x80000000u : 0u);
            bins[j] = (neg ? 0u : 512u) + (pb >> 21);
        }
        ce0d += (double)c0; ce1d += (double)c1;
        if (STORED) ((uint4*)pb_of(ws, BR))[idx[u]] = pk;
#pragma unroll
        for (int j = 0; j < 4; j++) {
            unsigned bj = bins[j];
            if (bj != 0xFFFFFFFFu) {
                unsigned cnt = 1;
#pragma unroll
                for (int k = j + 1; k < 4; k++)
                    if (bins[k] == bj) { cnt++; bins[k] = 0xFFFFFFFFu; }
                atomicAdd(&h[bj], cnt);
            }
        }
    }

    unsigned pn = posc | (negc << 16);
    pn = wred_u(pn);
    double C0 = wred_d(ce0d);
    double C1 = wred_d(ce1d);
    __shared__ unsigned spn[4];
    __shared__ double sc0[4], sc1[4];
    int w = t >> 6, lane = t & 63;
    if (lane == 0) { spn[w] = pn; sc0[w] = C0; sc1[w] = C1; }
    __syncthreads();   // also orders LDS hist atomics before flush
    if (t == 0) {
        pn_part(ws)[gblk] = spn[0] + spn[1] + spn[2] + spn[3];
        cep_part(ws)[gblk] = make_double2(sc0[0] + sc0[1] + sc0[2] + sc0[3],
                                          sc1[0] + sc1[1] + sc1[2] + sc1[3]);
    }
    const int rep = gblk & (REP1 - 1);
    unsigned* H = h1_of(ws, BR);
    for (int i = t; i < 1024; i += BLK) {
        unsigned v = h[i];
        if (v) atomicAdd(&H[(size_t)i * REP1 + rep], v);
    }
}

template <int BR>
__device__ void bbox_body(const float4* __restrict__ bbox, const float4* __restrict__ gmask,
                          const float4* __restrict__ glabel, void* ws, int blk, int gblk)
{
    constexpr int HW4 = BR ? HW1_4 : HW0_4;
    constexpr int NT  = (BR ? BBLK1 : BBLK0) * BLK;
    const int t = threadIdx.x;
    const int i0 = blk * BLK + t;

    float4 pb4[5], gm[5], gl[5];
#pragma unroll
    for (int k = 0; k < 5; k++) {
        int i = i0 + k * NT;
        int b = i / (4 * HW4);
        int off = i + (2 * b + 2) * HW4;
        pb4[k] = bbox[i];
        gm[k]  = gmask[off];
        gl[k]  = glabel[off];
    }
    SCHED_FENCE();   // all 15 loads issued before compute

    float d2 = 0.0f, ms = 0.0f;
#pragma unroll
    for (int k = 0; k < 5; k++) {
#pragma unroll
        for (int j = 0; j < 4; j++) {
            float m = (&gm[k].x)[j];
            float d = ((&pb4[k].x)[j] - (&gl[k].x)[j]) * m;
            d2 += d * d;
            ms += m;
        }
    }
    double D = wred_d((double)d2);
    double M = wred_d((double)ms);
    __shared__ double sdd[4], sdm[4];
    int w = t >> 6, lane = t & 63;
    if (lane == 0) { sdd[w] = D; sdm[w] = M; }
    __syncthreads();
    if (t == 0)
        dm_part(ws)[gblk] = make_double2(sdd[0] + sdd[1] + sdd[2] + sdd[3],
                                         sdm[0] + sdm[1] + sdm[2] + sdm[3]);
}

template <bool STORED>
__global__ __launch_bounds__(256, 2) void pass1(
    const float4* __restrict__ sc0, const float4* __restrict__ bb0,
    const float4* __restrict__ mk0, const float4* __restrict__ lb0,
    const float4* __restrict__ sc1, const float4* __restrict__ bb1,
    const float4* __restrict__ mk1, const float4* __restrict__ lb1,
    void* ws)
{
    __shared__ unsigned h[1024];
    const int bid = blockIdx.x;
    if (bid < SBT) {
        for (int i = threadIdx.x; i < 1024; i += BLK) h[i] = 0;
        __syncthreads();
        if (bid < SB0) score_body<0, STORED>(sc0, lb0, ws, bid, bid, h);
        else           score_body<1, STORED>(sc1, lb1, ws, bid - SB0, bid, h);
    } else if (bid < SBT + BBLK0) {
        bbox_body<0>(bb0, mk0, lb0, ws, bid - SBT, bid - SBT);
    } else {
        bbox_body<1>(bb1, mk1, lb1, ws, bid - SBT - BBLK0, bid - SBT);
    }
}

// ---------------- redundant per-block selects ----------------
// All inputs (PN, h1, h2, cnt1, cnt2, Acc.pn) are finalized integers at the
// preceding kernel boundary, so every block computes the SAME result.

struct Sel1R { unsigned P, negn, haspos, sel1, tnext, done, hA0; };

// shared scratch: pref[256], shv[4], shq[4]
__device__ void sel1_common(int br, unsigned P, unsigned negn, const unsigned* C1raw,
                            bool rawRep, Sel1R& R, unsigned* pref, unsigned* shv)
{
    const int t = threadIdx.x;
    const unsigned N = br ? N1 : N0;
    const unsigned haspos = (P > 0) ? 1u : 0u;
    unsigned k = haspos ? ((5u * P < negn) ? 5u * P : negn) : (N / 10u);
    unsigned target = (k < 1u) ? 1u : k;
    if (target > N) target = N;

    unsigned cnt[2], ssum = 0;
#pragma unroll
    for (int j = 0; j < 2; j++) {
        int i = t * 2 + j;
        unsigned s;
        if (rawRep) {
            const uint4* p = (const uint4*)(C1raw + (size_t)i * REP1);
            s = 0;
#pragma unroll
            for (int r = 0; r < REP1 / 4; r++) { uint4 q = p[r]; s += q.x + q.y + q.z + q.w; }
        } else {
            s = C1raw[i];
        }
        if (i == 0) shv[2] = s;
        if (!haspos) {
            if (rawRep) {
                const uint4* p2 = (const uint4*)(C1raw + (size_t)(512 + i) * REP1);
#pragma unroll
                for (int r = 0; r < REP1 / 4; r++) { uint4 q = p2[r]; s += q.x + q.y + q.z + q.w; }
            } else {
                s += C1raw[512 + i];
            }
        }
        unsigned cv = s + ((haspos && i == 0) ? (N - negn) : 0u);
        cnt[j] = cv; ssum += cv;
    }
    if (t == 0) { shv[0] = 0; shv[1] = 1; }
    __syncthreads();
    pref[t] = ssum;
    __syncthreads();
    for (int off = 1; off < 256; off <<= 1) {
        unsigned x = (t >= off) ? pref[t - off] : 0u;
        __syncthreads();
        pref[t] += x;
        __syncthreads();
    }
    unsigned tot = pref[255];
    if (target > tot) target = tot;
    unsigned before = pref[t] - ssum;
#pragma unroll
    for (int j = 0; j < 2; j++) {
        if (tot && before < target && before + cnt[j] >= target) {
            shv[0] = (unsigned)(t * 2 + j);
            shv[1] = target - before;
        }
        before += cnt[j];
    }
    __syncthreads();
    R.P = P; R.negn = negn; R.haspos = haspos;
    R.sel1 = shv[0]; R.tnext = shv[1]; R.hA0 = shv[2];
    R.done = (haspos && R.sel1 == 0 && R.hA0 == 0) ? 1u : 0u;
    __syncthreads();   // protect shv/pref reuse by caller
}

// version used by refine2': raw PN + raw h1
__device__ void compute_sel1_raw(void* ws, int br, Sel1R& R,
                                 unsigned* pref, unsigned* shv, ull* shq)
{
    const int t = threadIdx.x;
    const unsigned* PN = pn_part(ws);
    const int lo = br ? SB0 : 0, hi = br ? SBT : SB0;
    ull pn = 0;
    for (int i = lo + t; i < hi; i += BLK) {
        unsigned v = PN[i];
        pn += (ull)(v & 0xFFFFu) | ((ull)(v >> 16) << 32);
    }
    pn = wred_q(pn);
    int w = t >> 6;
    if ((t & 63) == 0) shq[w] = pn;
    __syncthreads();
    ull tot = shq[0] + shq[1] + shq[2] + shq[3];
    unsigned P = (unsigned)(tot & 0xFFFFFFFFull);
    unsigned negn = (unsigned)(tot >> 32);
    __syncthreads();
    sel1_common(br, P, negn, h1_of(ws, br), true, R, pref, shv);
}

// version used by refine3'/scan_final: Acc.pn + compact cnt1
__device__ void compute_sel1_compact(void* ws, int br, Sel1R& R,
                                     unsigned* pref, unsigned* shv)
{
    ull pn = acc_of(ws)[br].pn;
    unsigned P = (unsigned)(pn & 0xFFFFFFFFull);
    unsigned negn = (unsigned)(pn >> 32);
    sel1_common(br, P, negn, cnt1_of(ws) + (size_t)br * 1024, false, R, pref, shv);
}

// level-2 select; C2raw either raw h2 (rep-major, rawRep) or compact cnt2
__device__ void compute_sel2(const unsigned* C2raw, bool rawRep, unsigned target,
                             unsigned& sel2, unsigned& tnext, unsigned* pref, unsigned* shv)
{
    const int t = threadIdx.x;
    unsigned cnt[8], ssum = 0;
#pragma unroll
    for (int j = 0; j < 8; j++) {
        int i = t * 8 + j;
        unsigned s;
        if (rawRep) {
            const uint4* p = (const uint4*)(C2raw + (size_t)i * REP2);
            uint4 q0 = p[0], q1 = p[1];
            s = q0.x + q0.y + q0.z + q0.w + q1.x + q1.y + q1.z + q1.w;
        } else {
            s = C2raw[i];
        }
        cnt[j] = s; ssum += s;
    }
    if (t == 0) { shv[0] = 0; shv[1] = 1; }
    __syncthreads();
    pref[t] = ssum;
    __syncthreads();
    for (int off = 1; off < 256; off <<= 1) {
        unsigned x = (t >= off) ? pref[t - off] : 0u;
        __syncthreads();
        pref[t] += x;
        __syncthreads();
    }
    unsigned tot = pref[255];
    if (target > tot) target = tot;
    unsigned before = pref[t] - ssum;
#pragma unroll
    for (int j = 0; j < 8; j++) {
        if (tot && before < target && before + cnt[j] >= target) {
            shv[0] = (unsigned)(t * 8 + j);
            shv[1] = target - before;
        }
        before += cnt[j];
    }
    __syncthreads();
    sel2 = shv[0]; tnext = shv[1];
    __syncthreads();
}

// ---- refine2 body (ctrl reads replaced by params) ----
template <int BR, bool STORED>
__device__ void refine2_body(const float4* __restrict__ score, const float4* __restrict__ glabel,
                             void* ws, int blk, unsigned* h, unsigned haspos, unsigned sel1)
{
    constexpr int T = BR ? RT1 : RT0;
    constexpr int HW4 = BR ? HW1_4 : HW0_4;
    const int base = blk * BLK + (int)threadIdx.x;

    unsigned pk[16];
    if (STORED) {
        const uint4* pb4 = (const uint4*)pb_of(ws, BR);
#pragma unroll
        for (int i = 0; i < 4; i++) {
            uint4 q = pb4[base + i * T];
            pk[i*4+0]=q.x; pk[i*4+1]=q.y; pk[i*4+2]=q.z; pk[i*4+3]=q.w;
        }
    } else {
#pragma unroll
        for (int i = 0; i < 4; i++) {
            int id = base + i * T;
            int b = id / HW4, r = id - b * HW4;
            float4 s0 = score[(size_t)(b*2)*HW4 + r];
            float4 s1 = score[(size_t)(b*2+1)*HW4 + r];
            float4 g1 = glabel[(size_t)(b*6+1)*HW4 + r];
#pragma unroll
            for (int j = 0; j < 4; j++) {
                float a=(&s0.x)[j], cc=(&s1.x)[j];
                float m=fmaxf(a,cc);
                float e0=__expf(a-m), e1=__expf(cc-m);
                float p1=e1/(e0+e1);
                pk[i*4+j] = __float_as_uint(p1) | (((&g1.x)[j] > 0.5f) ? 0x80000000u : 0u);
            }
        }
    }
    unsigned z = 0;
#pragma unroll
    for (int i = 0; i < 4; i++) {
        unsigned bins[4];
#pragma unroll
        for (int j = 0; j < 4; j++) {
            unsigned raw = pk[i*4+j], pbv = raw & 0x7FFFFFFFu;
            unsigned npb = haspos ? ((raw >> 31) ? pbv : 0u) : pbv;
            bool m = (npb >> 21) == sel1;
            if (m && npb == 0) { z++; bins[j] = 0xFFFFFFFFu; }
            else bins[j] = m ? ((npb >> 10) & 0x7FFu) : 0xFFFFFFFFu;
        }
#pragma unroll
        for (int j = 0; j < 4; j++) {
            unsigned bj = bins[j];
            if (bj != 0xFFFFFFFFu) {
                unsigned cnt = 1;
#pragma unroll
                for (int k = j + 1; k < 4; k++)
                    if (bins[k] == bj) { cnt++; bins[k] = 0xFFFFFFFFu; }
                atomicAdd(&h[bj], cnt);
            }
        }
    }
    if (z) atomicAdd(&h[0], z);
}

// ---- refine3 body (ctrl reads replaced by params) ----
template <int BR, bool STORED>
__device__ void refine3_body(const float4* __restrict__ score, const float4* __restrict__ glabel,
                             void* ws, int blk, int gblk, ull* h,
                             unsigned haspos, unsigned sel1, unsigned sel2)
{
    const unsigned sel12 = (sel1 << 11) | sel2;
    constexpr int T = BR ? RT1 : RT0;
    constexpr int HW4 = BR ? HW1_4 : HW0_4;
    constexpr int HW  = BR ? HW1 : HW0;
    const int base = blk * BLK + (int)threadIdx.x;
    const float* glab_s = (const float*)glabel;

    unsigned pk[16];
    float g1v[16];
    if (STORED) {
        const uint4* pb4 = (const uint4*)pb_of(ws, BR);
#pragma unroll
        for (int i = 0; i < 4; i++) {
            uint4 q = pb4[base + i * T];
            pk[i*4+0]=q.x; pk[i*4+1]=q.y; pk[i*4+2]=q.z; pk[i*4+3]=q.w;
        }
    } else {
#pragma unroll
        for (int i = 0; i < 4; i++) {
            int id = base + i * T;
            int b = id / HW4, r = id - b * HW4;
            float4 s0 = score[(size_t)(b*2)*HW4 + r];
            float4 s1 = score[(size_t)(b*2+1)*HW4 + r];
            float4 g1 = glabel[(size_t)(b*6+1)*HW4 + r];
#pragma unroll
            for (int j = 0; j < 4; j++) {
                float a=(&s0.x)[j], cc=(&s1.x)[j];
                float m=fmaxf(a,cc);
                float e0=__expf(a-m), e1=__expf(cc-m);
                float p1=e1/(e0+e1);
                pk[i*4+j] = __float_as_uint(p1) | (((&g1.x)[j] > 0.5f) ? 0x80000000u : 0u);
                g1v[i*4+j] = (&g1.x)[j];
            }
        }
    }

    ull cnt_lt = 0;
    double ce_lt = 0.0;
    ull zpack = 0;
#pragma unroll
    for (int i = 0; i < 4; i++) {
#pragma unroll
        for (int j = 0; j < 4; j++) {
            unsigned raw = pk[i*4+j], pbv = raw & 0x7FFFFFFFu;
            unsigned npb = haspos ? ((raw >> 31) ? pbv : 0u) : pbv;
            bool iszero = (npb == 0);
            if (iszero && sel12 != 0) continue;  // accounted via base in scan_final
            unsigned b1 = npb >> 21, b2 = (npb >> 10) & 0x7FFu;
            bool lt = (b1 < sel1) || (b1 == sel1 && b2 < sel2);
            bool eq = ((npb >> 10) == sel12);
            if (lt || eq) {
                float g1s;
                if (STORED) {
                    int px = (base + i * T) * 4 + j;
                    int bb = px / HW, rr = px - bb * HW;
                    g1s = glab_s[(size_t)(bb * 6 + 1) * HW + rr];
                } else {
                    g1s = g1v[i*4+j];
                }
                float ce = -g1s * __logf(__uint_as_float(pbv));
                if (lt) { cnt_lt++; ce_lt += (double)ce; }
                else {
                    ull v = (1ull << 40) | (ull)__float2uint_rn(ce * CE_SCALE);
                    if (iszero) zpack += v;
                    else atomicAdd(&h[npb & 0x3FFu], v);
                }
            }
        }
    }
    if (zpack) atomicAdd(&h[0], zpack);

    ull CL = wred_q(cnt_lt);
    double CE = wred_d(ce_lt);
    __shared__ ull sq[4];
    __shared__ double sd[4];
    int t = threadIdx.x, w = t >> 6, lane = t & 63;
    if (lane == 0) { sq[w] = CL; sd[w] = CE; }
    __syncthreads();   // also orders LDS hist atomics before flush
    if (t == 0) {
        ull totc = sq[0] + sq[1] + sq[2] + sq[3];
        double totd = sd[0] + sd[1] + sd[2] + sd[3];
        ull* F = fin_of(ws, BR) + (size_t)(gblk & (REP2 - 1)) * 2;
        if (totc) atomicAdd(&F[0], totc);
        if (totd != 0.0) atomicAdd((double*)&F[1], totd);
    }
    const int rep = gblk & (REP2 - 1);
    ull* H = h3_of(ws, BR);
    for (int i = t; i < 1024; i += BLK) {
        ull v = h[i];
        if (v) atomicAdd(&H[(size_t)i * REP2 + rep], v);
    }
}

// ---- refine2': spare compaction duties + per-block select1 + tile work ----
template <bool STORED>
__global__ __launch_bounds__(256) void refine2_k2(
    const float4* __restrict__ sc0, const float4* __restrict__ lb0,
    const float4* __restrict__ sc1, const float4* __restrict__ lb1, void* ws)
{
    __shared__ unsigned h[2048];
    __shared__ unsigned pref[256];
    __shared__ unsigned shv[4];
    __shared__ ull shq[4];
    const int t = threadIdx.x;
    const int bid = blockIdx.x;

    // spare duties: compact h1 -> cnt1; reduce PN/CEP -> Acc; reduce DM -> Acc.
    if (bid < 8) {
        const int job = bid * BLK + t;            // 0..2047
        const int jbr = job >> 10, bin = job & 1023;
        const uint4* p = (const uint4*)(h1_of(ws, jbr) + (size_t)bin * REP1);
        unsigned s = 0;
#pragma unroll
        for (int r = 0; r < REP1 / 4; r++) { uint4 q = p[r]; s += q.x + q.y + q.z + q.w; }
        cnt1_of(ws)[job] = s;
    } else if (bid < 16) {
        const int i = (bid - 8) * BLK + t;        // 0..2047, valid < SBT
        ull pv = 0; double a = 0.0, b = 0.0; bool hi = false;
        if (i < SBT) {
            unsigned v = pn_part(ws)[i];
            double2 ce = cep_part(ws)[i];
            pv = (ull)(v & 0xFFFFu) | ((ull)(v >> 16) << 32);
            a = ce.x; b = ce.y; hi = (i >= SB0);
        }
        ull p0 = hi ? 0 : pv, p1 = hi ? pv : 0;
        double a0 = hi ? 0.0 : a, a1 = hi ? a : 0.0;
        double b0 = hi ? 0.0 : b, b1 = hi ? b : 0.0;
        p0 = wred_q(p0); p1 = wred_q(p1);
        a0 = wred_d(a0); a1 = wred_d(a1); b0 = wred_d(b0); b1 = wred_d(b1);
        if ((t & 63) == 0) {
            Acc* A = acc_of(ws);
            if (p0) atomicAdd(&A[0].pn, p0);
            if (p1) atomicAdd(&A[1].pn, p1);
            if (a0 != 0.0) atomicAdd(&A[0].ce0, a0);
            if (a1 != 0.0) atomicAdd(&A[1].ce0, a1);
            if (b0 != 0.0) atomicAdd(&A[0].ce1, b0);
            if (b1 != 0.0) atomicAdd(&A[1].ce1, b1);
        }
    } else if (bid < 32) {
        const int i = (bid - 16) * BLK + t;       // 0..4095, valid < 3200
        double d = 0.0, m = 0.0; bool hi = false;
        if (i < BBLK0 + BBLK1) {
            double2 v = dm_part(ws)[i];
            d = v.x; m = v.y; hi = (i >= BBLK0);
        }
        double d0 = hi ? 0.0 : d, d1 = hi ? d : 0.0;
        double m0 = hi ? 0.0 : m, m1 = hi ? m : 0.0;
        d0 = wred_d(d0); d1 = wred_d(d1); m0 = wred_d(m0); m1 = wred_d(m1);
        if ((t & 63) == 0) {
            Acc* A = acc_of(ws);
            if (d0 != 0.0) atomicAdd(&A[0].d2, d0);
            if (d1 != 0.0) atomicAdd(&A[1].d2, d1);
            if (m0 != 0.0) atomicAdd(&A[0].ms, m0);
            if (m1 != 0.0) atomicAdd(&A[1].ms, m1);
        }
    }

    const int br  = (bid < RB0) ? 0 : 1;
    const int blk = (bid < RB0) ? bid : bid - RB0;

    Sel1R s1;
    compute_sel1_raw(ws, br, s1, pref, shv, shq);
    if (s1.done) return;

    for (int i = t; i < 2048; i += BLK) h[i] = 0;
    __syncthreads();
    if (br == 0) refine2_body<0, STORED>(sc0, lb0, ws, blk, h, s1.haspos, s1.sel1);
    else         refine2_body<1, STORED>(sc1, lb1, ws, blk, h, s1.haspos, s1.sel1);
    __syncthreads();
    const int rep = bid & (REP2 - 1);
    unsigned* H = h2_of(ws, br);
    for (int i = t; i < 2048; i += BLK) {
        unsigned v = h[i];
        if (v) atomicAdd(&H[(size_t)i * REP2 + rep], v);
    }
}

// ---- refine3': spare h2 compaction + per-block select1 (compact) + select2 (raw h2) + tile ----
template <bool STORED>
__global__ __launch_bounds__(256) void refine3_k2(
    const float4* __restrict__ sc0, const float4* __restrict__ lb0,
    const float4* __restrict__ sc1, const float4* __restrict__ lb1, void* ws)
{
    __shared__ ull h[1024];
    __shared__ unsigned pref[256];
    __shared__ unsigned shv[4];
    const int t = threadIdx.x;
    const int bid = blockIdx.x;

    // spare duty: compact h2 -> cnt2 (for scan_final)
    if (bid < 16) {
        const int job = bid * BLK + t;            // 0..4095
        const int jbr = job >> 11, bin = job & 2047;
        const uint4* p = (const uint4*)(h2_of(ws, jbr) + (size_t)bin * REP2);
        uint4 q0 = p[0], q1 = p[1];
        cnt2_of(ws)[job] = q0.x + q0.y + q0.z + q0.w + q1.x + q1.y + q1.z + q1.w;
    }

    const int br  = (bid < RB0) ? 0 : 1;
    const int blk = (bid < RB0) ? bid : bid - RB0;

    Sel1R s1;
    compute_sel1_compact(ws, br, s1, pref, shv);
    if (s1.done) return;

    unsigned sel2, tnx2;
    compute_sel2(h2_of(ws, br), true, s1.tnext, sel2, tnx2, pref, shv);

    for (int i = t; i < 1024; i += BLK) h[i] = 0;
    __syncthreads();
    if (br == 0) refine3_body<0, STORED>(sc0, lb0, ws, blk, bid, h, s1.haspos, s1.sel1, sel2);
    else         refine3_body<1, STORED>(sc1, lb1, ws, blk, bid, h, s1.haspos, s1.sel1, sel2);
}

// ---- scan_final: single small block on compact data + h3/fin ----
__global__ __launch_bounds__(256) void scan_final(void* ws, float* out)
{
    const int t = threadIdx.x;
    __shared__ unsigned pref[256];
    __shared__ unsigned shv[4];
    __shared__ ull qscr[4];
    __shared__ double sls[2], slb[2];

    for (int br = 0; br < 2; br++) {
        const unsigned N = br ? N1 : N0;
        Acc* A = acc_of(ws) + br;
        ull pn = A->pn;
        unsigned P = (unsigned)(pn & 0xFFFFFFFFull);
        unsigned negn = (unsigned)(pn >> 32);
        double CE0 = A->ce0, CE1NN = A->ce1;
        double D = A->d2, M = A->ms;
        double lb = (M > 0.0) ? D / fmax(M, 1e-8) : 0.0;

        Sel1R s1;
        compute_sel1_compact(ws, br, s1, pref, shv);

        if (s1.done) {
            if (t == 0) {
                double cntd = (double)P + (double)(N - negn);
                if (cntd < 1.0) cntd = 1.0;
                sls[br] = (CE0 + CE1NN) / cntd;
                slb[br] = lb;
            }
            __syncthreads();
            continue;
        }

        unsigned sel2, tnx2;
        compute_sel2(cnt2_of(ws) + (size_t)br * 2048, false, s1.tnext, sel2, tnx2, pref, shv);

        // level-3 select on h3 (reduce REP2 inline)
        const ull* H3 = h3_of(ws, br);
        ull cev[4]; unsigned cnt[4], ssum = 0;
#pragma unroll
        for (int j = 0; j < 4; j++) {
            int i = t * 4 + j;
            ull e = 0;
#pragma unroll
            for (int r = 0; r < REP2; r++) e += H3[(size_t)i * REP2 + r];
            cev[j] = e;
            cnt[j] = (unsigned)(e >> 40);
            ssum += cnt[j];
        }
        unsigned target = tnx2;
        if (t == 0) { shv[0] = 0; shv[1] = 1; }
        __syncthreads();
        pref[t] = ssum;
        __syncthreads();
        for (int off = 1; off < 256; off <<= 1) {
            unsigned x = (t >= off) ? pref[t - off] : 0u;
            __syncthreads();
            pref[t] += x;
            __syncthreads();
        }
        unsigned tot = pref[255];
        if (target > tot) target = tot;
        unsigned before = pref[t] - ssum;
#pragma unroll
        for (int j = 0; j < 4; j++) {
            if (tot && before < target && before + cnt[j] >= target) {
                shv[0] = (unsigned)(t * 4 + j);
                shv[1] = target - before;
            }
            before += cnt[j];
        }
        __syncthreads();
        unsigned sel3 = shv[0];

        ull cei = 0;
#pragma unroll
        for (int j = 0; j < 4; j++) {
            unsigned bin = (unsigned)(t * 4 + j);
            if (bin <= sel3) cei += cev[j];
        }
        cei = wred_q(cei);
        int w = t >> 6;
        if ((t & 63) == 0) qscr[w] = cei;
        __syncthreads();
        if (t == 0) {
            ull CEI = qscr[0] + qscr[1] + qscr[2] + qscr[3];
            const ull* F = fin_of(ws, br);
            ull cl = 0; double cel = 0.0;
            for (int r = 0; r < REP2; r++) {
                cl += F[r * 2];
                cel += ((const double*)F)[r * 2 + 1];
            }
            unsigned sel12 = (s1.sel1 << 11) | sel2;
            double basec = (s1.haspos && sel12 != 0) ? (double)(N - negn) : 0.0;
            double basee = (s1.haspos && sel12 != 0) ? CE1NN : 0.0;
            double cntd = (double)P + basec + (double)cl + (double)(CEI >> 40);
            if (cntd < 1.0) cntd = 1.0;
            double ce = CE0 + basee + cel + (double)(CEI & MASK40) / (double)CE_SCALE;
            sls[br] = ce / cntd;
            slb[br] = lb;
        }
        __syncthreads();
    }

    if (t == 0) {
        out[0] = (float)(sls[0] + slb[0] + sls[1] + slb[1]);
        out[1] = (float)sls[0];
        out[2] = (float)slb[0];
        out[3] = (float)sls[1];
        out[4] = (float)slb[1];
    }
}

// ---------------- host ----------------
template <bool S>
static void run_pipeline(const float4* sc0, const float4* bb0, const float4* mk0, const float4* lb0,
                         const float4* sc1, const float4* bb1, const float4* mk1, const float4* lb1,
                         void* ws, float* out, hipStream_t stream)
{
    pass1<S><<<P1_GRID, BLK, 0, stream>>>(sc0, bb0, mk0, lb0, sc1, bb1, mk1, lb1, ws);
    refine2_k2<S><<<GRID_R, BLK, 0, stream>>>(sc0, lb0, sc1, lb1, ws);
    refine3_k2<S><<<GRID_R, BLK, 0, stream>>>(sc0, lb0, sc1, lb1, ws);
    scan_final<<<1, BLK, 0, stream>>>(ws, out);
}

extern "C" void kernel_launch(void* const* d_in, const int* in_sizes, int n_in,
                              void* d_out, int out_size, void* d_ws, size_t ws_size,
                              hipStream_t stream)
{
    (void)in_sizes; (void)n_in; (void)out_size;
    const float4* sc0 = (const float4*)d_in[0];
    const float4* bb0 = (const float4*)d_in[1];
    const float4* mk0 = (const float4*)d_in[2];
    const float4* lb0 = (const float4*)d_in[3];
    const float4* sc1 = (const float4*)d_in[4];
    const float4* bb1 = (const float4*)d_in[5];
    const float4* mk1 = (const float4*)d_in[6];
    const float4* lb1 = (const float4*)d_in[7];
    float* out = (float*)d_out;

    zero_ws_k<<<(ZERO_V4 + BLK - 1) / BLK, BLK, 0, stream>>>((uint4*)d_ws, ZERO_V4);

    if (ws_size >= WS_NEED)
        run_pipeline<true>(sc0, bb0, mk0, lb0, sc1, bb1, mk1, lb1, d_ws, out, stream);
    else
        run_pipeline<false>(sc0, bb0, mk0, lb0, sc1, bb1, mk1, lb1, d_ws, out, stream);
}

// Round 6
// 309.715 us; speedup vs baseline: 3.3292x; 1.0051x over previous
//
#include <hip/hip_runtime.h>

using ull = unsigned long long;

// ---------------- problem constants ----------------
constexpr int NB  = 32;
constexpr int HW0 = 320 * 320;
constexpr int HW1 = 160 * 160;
constexpr int N0  = NB * HW0;            // 3,276,800
constexpr int N1  = NB * HW1;            // 819,200
constexpr int HW0_4 = HW0 / 4;
constexpr int HW1_4 = HW1 / 4;
constexpr int BLK = 256;

// score blocks: 4 uint4-packs (16 px) per thread -> 1024 packs per block
constexpr int SB0 = N0 / 4 / 1024;       // 800
constexpr int SB1 = N1 / 4 / 1024;       // 200
constexpr int SBT = SB0 + SB1;           // 1000
// bbox blocks: 5 float4 per stream per thread, fully unrolled
constexpr int BBLK0 = 2560, BBLK1 = 640; // 3,276,800/(2560*256)=5 ; 819,200/(640*256)=5
constexpr int P1_GRID = SBT + BBLK0 + BBLK1;   // 4200
// refine: 4 uint4-packs (16 px) per thread
constexpr int RB0 = 800, RB1 = 200, GRID_R = RB0 + RB1;
constexpr int RT0 = RB0 * BLK;           // 204,800 (uint4 stride)
constexpr int RT1 = RB1 * BLK;           // 51,200

constexpr float CE_SCALE = 16384.0f;
constexpr ull MASK40 = (1ull << 40) - 1;
constexpr int REP1 = 32, REP2 = 8;

// ---------------- workspace layout (bytes) ----------------
constexpr size_t CTRL_OFF = 0;                                   // (reserved)
constexpr size_t ACC_OFF  = 256;                                 // Acc[2] (within zeroed page)
constexpr size_t H1_OFF  = 4096;                                 // u32 [2][1024][REP1] (bin-major)
constexpr size_t H2_OFF  = H1_OFF + (size_t)2 * 1024 * REP1 * 4; // u32 [2][2048][REP2]
constexpr size_t H3_OFF  = H2_OFF + (size_t)2 * 2048 * REP2 * 4; // u64 [2][1024][REP2]
constexpr size_t FIN_OFF = H3_OFF + (size_t)2 * 1024 * REP2 * 8; // [2][REP2][2] u64 cnt, double ce
constexpr size_t ZERO_END = FIN_OFF + 2 * REP2 * 16;             // 528,640
constexpr int    ZERO_V4  = (int)(ZERO_END / 16);                // 33,040 uint4s
constexpr size_t PN_OFF  = ZERO_END;                             // u32[SBT]
constexpr size_t CEP_OFF = PN_OFF + SBT * 4;                     // double2[SBT] (ce0, ce1nn)
constexpr size_t DM_OFF  = CEP_OFF + (size_t)SBT * 16;           // double2[3200] (d2, ms)
// compact reduction outputs (written-before-read each launch; no zeroing needed)
constexpr size_t CN1_OFF = DM_OFF + (size_t)3200 * 16;           // u32[2][1024]
constexpr size_t CN2_OFF = CN1_OFF + (size_t)2 * 1024 * 4;       // u32[2][2048]
constexpr size_t CEV_OFF = CN2_OFF + (size_t)2 * 2048 * 4;       // u64[2][1024] (reserved)
constexpr size_t PB_OFF  = ((CEV_OFF + (size_t)2 * 1024 * 8 + 255) / 256) * 256;
constexpr size_t WS_NEED = PB_OFF + (size_t)(N0 + N1) * 4;       // ~17.05 MB

struct Acc { ull pn; double ce0, ce1, d2, ms; };

__device__ inline Acc*      acc_of(void* ws)       { return (Acc*)((char*)ws + ACC_OFF); }
__device__ inline unsigned* h1_of(void* ws, int br) { return (unsigned*)((char*)ws + H1_OFF) + (size_t)br * 1024 * REP1; }
__device__ inline unsigned* h2_of(void* ws, int br) { return (unsigned*)((char*)ws + H2_OFF) + (size_t)br * 2048 * REP2; }
__device__ inline ull*      h3_of(void* ws, int br) { return (ull*)((char*)ws + H3_OFF) + (size_t)br * 1024 * REP2; }
__device__ inline ull*      fin_of(void* ws, int br) { return (ull*)((char*)ws + FIN_OFF) + (size_t)br * REP2 * 2; }
__device__ inline unsigned* pn_part(void* ws)  { return (unsigned*)((char*)ws + PN_OFF); }
__device__ inline double2*  cep_part(void* ws) { return (double2*)((char*)ws + CEP_OFF); }
__device__ inline double2*  dm_part(void* ws)  { return (double2*)((char*)ws + DM_OFF); }
__device__ inline unsigned* cnt1_of(void* ws)  { return (unsigned*)((char*)ws + CN1_OFF); }
__device__ inline unsigned* cnt2_of(void* ws)  { return (unsigned*)((char*)ws + CN2_OFF); }
__device__ inline unsigned* pb_of(void* ws, int br) { return (unsigned*)((char*)ws + PB_OFF) + (br ? (size_t)N0 : 0); }

// ---------------- reduce helpers ----------------
__device__ __forceinline__ unsigned wred_u(unsigned v) {
#pragma unroll
    for (int o = 32; o > 0; o >>= 1) v += __shfl_down(v, o, 64);
    return v;
}
__device__ __forceinline__ ull wred_q(ull v) {
#pragma unroll
    for (int o = 32; o > 0; o >>= 1) v += __shfl_down(v, o, 64);
    return v;
}
__device__ __forceinline__ double wred_d(double v) {
#pragma unroll
    for (int o = 32; o > 0; o >>= 1) v += __shfl_down(v, o, 64);
    return v;
}

// Pin all 4 components of a float4 into live VGPRs at this program point.
// Volatile empty asm: IR passes cannot sink the feeding loads past it, and
// the register allocator must keep all components live -> forces the full
// load burst to issue before any compute (real MLP, unlike sched_barrier).
__device__ __forceinline__ void keep4(float4& v) {
    asm volatile("" : "+v"(v.x), "+v"(v.y), "+v"(v.z), "+v"(v.w));
}

// ---------------- kernels ----------------
__global__ __launch_bounds__(256) void zero_ws_k(uint4* p, int n) {
    int i = blockIdx.x * BLK + threadIdx.x;
    if (i < n) p[i] = make_uint4(0, 0, 0, 0);
}

// ---- pass1: forced 16-deep load burst (keep4), 16 px/thread score ----
template <int BR, bool STORED>
__device__ void score_body(const float4* __restrict__ score, const float4* __restrict__ glabel,
                           void* ws, int blk, int gblk, unsigned* h)
{
    constexpr int HW4 = BR ? HW1_4 : HW0_4;
    const int t = threadIdx.x;
    const int base = blk * 1024 + t;

    float4 s0[4], s1[4], g0[4], g1[4];
    int idx[4];
#pragma unroll
    for (int u = 0; u < 4; u++) {
        idx[u] = base + 256 * u;
        int b = idx[u] / HW4, r = idx[u] - b * HW4;
        const float4* sp = score  + (size_t)(b * 2) * HW4 + r;
        const float4* gp = glabel + (size_t)(b * 6) * HW4 + r;
        s0[u] = sp[0]; s1[u] = sp[HW4];
        g0[u] = gp[0]; g1[u] = gp[HW4];
    }
#pragma unroll
    for (int u = 0; u < 4; u++) { keep4(s0[u]); keep4(s1[u]); keep4(g0[u]); keep4(g1[u]); }

    unsigned posc = 0, negc = 0;
    double ce0d = 0.0, ce1d = 0.0;
#pragma unroll
    for (int u = 0; u < 4; u++) {
        uint4 pk;
        unsigned bins[4];
        float c0 = 0.0f, c1 = 0.0f;
#pragma unroll
        for (int j = 0; j < 4; j++) {
            float a = (&s0[u].x)[j], cc = (&s1[u].x)[j];
            float m = fmaxf(a, cc);
            float e0 = __expf(a - m), e1 = __expf(cc - m);
            float inv = 1.0f / (e0 + e1);
            float p0 = e0 * inv, p1 = e1 * inv;
            float l0 = (&g0[u].x)[j], l1 = (&g1[u].x)[j];
            bool pos = l0 > 0.5f, neg = l1 > 0.5f;
            posc += pos ? 1u : 0u;
            negc += neg ? 1u : 0u;
            if (pos)  c0 += -l0 * __logf(p0);
            if (!neg) c1 += -l1 * __logf(p1);
            unsigned pb = __float_as_uint(p1);
            (&pk.x)[j] = pb | (neg ? 0x80000000u : 0u);
            bins[j] = (neg ? 0u : 512u) + (pb >> 21);
        }
        ce0d += (double)c0; ce1d += (double)c1;
        if (STORED) ((uint4*)pb_of(ws, BR))[idx[u]] = pk;
#pragma unroll
        for (int j = 0; j < 4; j++) {
            unsigned bj = bins[j];
            if (bj != 0xFFFFFFFFu) {
                unsigned cnt = 1;
#pragma unroll
                for (int k = j + 1; k < 4; k++)
                    if (bins[k] == bj) { cnt++; bins[k] = 0xFFFFFFFFu; }
                atomicAdd(&h[bj], cnt);
            }
        }
    }

    unsigned pn = posc | (negc << 16);
    pn = wred_u(pn);
    double C0 = wred_d(ce0d);
    double C1 = wred_d(ce1d);
    __shared__ unsigned spn[4];
    __shared__ double sc0[4], sc1[4];
    int w = t >> 6, lane = t & 63;
    if (lane == 0) { spn[w] = pn; sc0[w] = C0; sc1[w] = C1; }
    __syncthreads();   // also orders LDS hist atomics before flush
    if (t == 0) {
        pn_part(ws)[gblk] = spn[0] + spn[1] + spn[2] + spn[3];
        cep_part(ws)[gblk] = make_double2(sc0[0] + sc0[1] + sc0[2] + sc0[3],
                                          sc1[0] + sc1[1] + sc1[2] + sc1[3]);
    }
    const int rep = gblk & (REP1 - 1);
    unsigned* H = h1_of(ws, BR);
    for (int i = t; i < 1024; i += BLK) {
        unsigned v = h[i];
        if (v) atomicAdd(&H[(size_t)i * REP1 + rep], v);
    }
}

template <int BR>
__device__ void bbox_body(const float4* __restrict__ bbox, const float4* __restrict__ gmask,
                          const float4* __restrict__ glabel, void* ws, int blk, int gblk)
{
    constexpr int HW4 = BR ? HW1_4 : HW0_4;
    constexpr int NT  = (BR ? BBLK1 : BBLK0) * BLK;
    const int t = threadIdx.x;
    const int i0 = blk * BLK + t;

    float4 pb4[5], gm[5], gl[5];
#pragma unroll
    for (int k = 0; k < 5; k++) {
        int i = i0 + k * NT;
        int b = i / (4 * HW4);
        int off = i + (2 * b + 2) * HW4;
        pb4[k] = bbox[i];
        gm[k]  = gmask[off];
        gl[k]  = glabel[off];
    }
#pragma unroll
    for (int k = 0; k < 5; k++) { keep4(pb4[k]); keep4(gm[k]); keep4(gl[k]); }

    float d2 = 0.0f, ms = 0.0f;
#pragma unroll
    for (int k = 0; k < 5; k++) {
#pragma unroll
        for (int j = 0; j < 4; j++) {
            float m = (&gm[k].x)[j];
            float d = ((&pb4[k].x)[j] - (&gl[k].x)[j]) * m;
            d2 += d * d;
            ms += m;
        }
    }
    double D = wred_d((double)d2);
    double M = wred_d((double)ms);
    __shared__ double sdd[4], sdm[4];
    int w = t >> 6, lane = t & 63;
    if (lane == 0) { sdd[w] = D; sdm[w] = M; }
    __syncthreads();
    if (t == 0)
        dm_part(ws)[gblk] = make_double2(sdd[0] + sdd[1] + sdd[2] + sdd[3],
                                         sdm[0] + sdm[1] + sdm[2] + sdm[3]);
}

template <bool STORED>
__global__ __launch_bounds__(256) void pass1(
    const float4* __restrict__ sc0, const float4* __restrict__ bb0,
    const float4* __restrict__ mk0, const float4* __restrict__ lb0,
    const float4* __restrict__ sc1, const float4* __restrict__ bb1,
    const float4* __restrict__ mk1, const float4* __restrict__ lb1,
    void* ws)
{
    __shared__ unsigned h[1024];
    const int bid = blockIdx.x;
    if (bid < SBT) {
        for (int i = threadIdx.x; i < 1024; i += BLK) h[i] = 0;
        __syncthreads();
        if (bid < SB0) score_body<0, STORED>(sc0, lb0, ws, bid, bid, h);
        else           score_body<1, STORED>(sc1, lb1, ws, bid - SB0, bid, h);
    } else if (bid < SBT + BBLK0) {
        bbox_body<0>(bb0, mk0, lb0, ws, bid - SBT, bid - SBT);
    } else {
        bbox_body<1>(bb1, mk1, lb1, ws, bid - SBT - BBLK0, bid - SBT);
    }
}

// ---------------- redundant per-block selects ----------------
// All inputs (PN, h1, h2, cnt1, cnt2, Acc.pn) are finalized integers at the
// preceding kernel boundary, so every block computes the SAME result.

struct Sel1R { unsigned P, negn, haspos, sel1, tnext, done, hA0; };

// shared scratch: pref[256], shv[4], shq[4]
__device__ void sel1_common(int br, unsigned P, unsigned negn, const unsigned* C1raw,
                            bool rawRep, Sel1R& R, unsigned* pref, unsigned* shv)
{
    const int t = threadIdx.x;
    const unsigned N = br ? N1 : N0;
    const unsigned haspos = (P > 0) ? 1u : 0u;
    unsigned k = haspos ? ((5u * P < negn) ? 5u * P : negn) : (N / 10u);
    unsigned target = (k < 1u) ? 1u : k;
    if (target > N) target = N;

    unsigned cnt[2], ssum = 0;
#pragma unroll
    for (int j = 0; j < 2; j++) {
        int i = t * 2 + j;
        unsigned s;
        if (rawRep) {
            const uint4* p = (const uint4*)(C1raw + (size_t)i * REP1);
            s = 0;
#pragma unroll
            for (int r = 0; r < REP1 / 4; r++) { uint4 q = p[r]; s += q.x + q.y + q.z + q.w; }
        } else {
            s = C1raw[i];
        }
        if (i == 0) shv[2] = s;
        if (!haspos) {
            if (rawRep) {
                const uint4* p2 = (const uint4*)(C1raw + (size_t)(512 + i) * REP1);
#pragma unroll
                for (int r = 0; r < REP1 / 4; r++) { uint4 q = p2[r]; s += q.x + q.y + q.z + q.w; }
            } else {
                s += C1raw[512 + i];
            }
        }
        unsigned cv = s + ((haspos && i == 0) ? (N - negn) : 0u);
        cnt[j] = cv; ssum += cv;
    }
    if (t == 0) { shv[0] = 0; shv[1] = 1; }
    __syncthreads();
    pref[t] = ssum;
    __syncthreads();
    for (int off = 1; off < 256; off <<= 1) {
        unsigned x = (t >= off) ? pref[t - off] : 0u;
        __syncthreads();
        pref[t] += x;
        __syncthreads();
    }
    unsigned tot = pref[255];
    if (target > tot) target = tot;
    unsigned before = pref[t] - ssum;
#pragma unroll
    for (int j = 0; j < 2; j++) {
        if (tot && before < target && before + cnt[j] >= target) {
            shv[0] = (unsigned)(t * 2 + j);
            shv[1] = target - before;
        }
        before += cnt[j];
    }
    __syncthreads();
    R.P = P; R.negn = negn; R.haspos = haspos;
    R.sel1 = shv[0]; R.tnext = shv[1]; R.hA0 = shv[2];
    R.done = (haspos && R.sel1 == 0 && R.hA0 == 0) ? 1u : 0u;
    __syncthreads();   // protect shv/pref reuse by caller
}

// version used by refine2': raw PN + raw h1
__device__ void compute_sel1_raw(void* ws, int br, Sel1R& R,
                                 unsigned* pref, unsigned* shv, ull* shq)
{
    const int t = threadIdx.x;
    const unsigned* PN = pn_part(ws);
    const int lo = br ? SB0 : 0, hi = br ? SBT : SB0;
    ull pn = 0;
    for (int i = lo + t; i < hi; i += BLK) {
        unsigned v = PN[i];
        pn += (ull)(v & 0xFFFFu) | ((ull)(v >> 16) << 32);
    }
    pn = wred_q(pn);
    int w = t >> 6;
    if ((t & 63) == 0) shq[w] = pn;
    __syncthreads();
    ull tot = shq[0] + shq[1] + shq[2] + shq[3];
    unsigned P = (unsigned)(tot & 0xFFFFFFFFull);
    unsigned negn = (unsigned)(tot >> 32);
    __syncthreads();
    sel1_common(br, P, negn, h1_of(ws, br), true, R, pref, shv);
}

// version used by refine3'/scan_final: Acc.pn + compact cnt1
__device__ void compute_sel1_compact(void* ws, int br, Sel1R& R,
                                     unsigned* pref, unsigned* shv)
{
    ull pn = acc_of(ws)[br].pn;
    unsigned P = (unsigned)(pn & 0xFFFFFFFFull);
    unsigned negn = (unsigned)(pn >> 32);
    sel1_common(br, P, negn, cnt1_of(ws) + (size_t)br * 1024, false, R, pref, shv);
}

// level-2 select; C2raw either raw h2 (rep-major, rawRep) or compact cnt2
__device__ void compute_sel2(const unsigned* C2raw, bool rawRep, unsigned target,
                             unsigned& sel2, unsigned& tnext, unsigned* pref, unsigned* shv)
{
    const int t = threadIdx.x;
    unsigned cnt[8], ssum = 0;
#pragma unroll
    for (int j = 0; j < 8; j++) {
        int i = t * 8 + j;
        unsigned s;
        if (rawRep) {
            const uint4* p = (const uint4*)(C2raw + (size_t)i * REP2);
            uint4 q0 = p[0], q1 = p[1];
            s = q0.x + q0.y + q0.z + q0.w + q1.x + q1.y + q1.z + q1.w;
        } else {
            s = C2raw[i];
        }
        cnt[j] = s; ssum += s;
    }
    if (t == 0) { shv[0] = 0; shv[1] = 1; }
    __syncthreads();
    pref[t] = ssum;
    __syncthreads();
    for (int off = 1; off < 256; off <<= 1) {
        unsigned x = (t >= off) ? pref[t - off] : 0u;
        __syncthreads();
        pref[t] += x;
        __syncthreads();
    }
    unsigned tot = pref[255];
    if (target > tot) target = tot;
    unsigned before = pref[t] - ssum;
#pragma unroll
    for (int j = 0; j < 8; j++) {
        if (tot && before < target && before + cnt[j] >= target) {
            shv[0] = (unsigned)(t * 8 + j);
            shv[1] = target - before;
        }
        before += cnt[j];
    }
    __syncthreads();
    sel2 = shv[0]; tnext = shv[1];
    __syncthreads();
}

// ---- refine2 body (ctrl reads replaced by params) ----
template <int BR, bool STORED>
__device__ void refine2_body(const float4* __restrict__ score, const float4* __restrict__ glabel,
                             void* ws, int blk, unsigned* h, unsigned haspos, unsigned sel1)
{
    constexpr int T = BR ? RT1 : RT0;
    constexpr int HW4 = BR ? HW1_4 : HW0_4;
    const int base = blk * BLK + (int)threadIdx.x;

    unsigned pk[16];
    if (STORED) {
        const uint4* pb4 = (const uint4*)pb_of(ws, BR);
#pragma unroll
        for (int i = 0; i < 4; i++) {
            uint4 q = pb4[base + i * T];
            pk[i*4+0]=q.x; pk[i*4+1]=q.y; pk[i*4+2]=q.z; pk[i*4+3]=q.w;
        }
    } else {
#pragma unroll
        for (int i = 0; i < 4; i++) {
            int id = base + i * T;
            int b = id / HW4, r = id - b * HW4;
            float4 s0 = score[(size_t)(b*2)*HW4 + r];
            float4 s1 = score[(size_t)(b*2+1)*HW4 + r];
            float4 g1 = glabel[(size_t)(b*6+1)*HW4 + r];
#pragma unroll
            for (int j = 0; j < 4; j++) {
                float a=(&s0.x)[j], cc=(&s1.x)[j];
                float m=fmaxf(a,cc);
                float e0=__expf(a-m), e1=__expf(cc-m);
                float p1=e1/(e0+e1);
                pk[i*4+j] = __float_as_uint(p1) | (((&g1.x)[j] > 0.5f) ? 0x80000000u : 0u);
            }
        }
    }
    unsigned z = 0;
#pragma unroll
    for (int i = 0; i < 4; i++) {
        unsigned bins[4];
#pragma unroll
        for (int j = 0; j < 4; j++) {
            unsigned raw = pk[i*4+j], pbv = raw & 0x7FFFFFFFu;
            unsigned npb = haspos ? ((raw >> 31) ? pbv : 0u) : pbv;
            bool m = (npb >> 21) == sel1;
            if (m && npb == 0) { z++; bins[j] = 0xFFFFFFFFu; }
            else bins[j] = m ? ((npb >> 10) & 0x7FFu) : 0xFFFFFFFFu;
        }
#pragma unroll
        for (int j = 0; j < 4; j++) {
            unsigned bj = bins[j];
            if (bj != 0xFFFFFFFFu) {
                unsigned cnt = 1;
#pragma unroll
                for (int k = j + 1; k < 4; k++)
                    if (bins[k] == bj) { cnt++; bins[k] = 0xFFFFFFFFu; }
                atomicAdd(&h[bj], cnt);
            }
        }
    }
    if (z) atomicAdd(&h[0], z);
}

// ---- refine3 body (ctrl reads replaced by params) ----
template <int BR, bool STORED>
__device__ void refine3_body(const float4* __restrict__ score, const float4* __restrict__ glabel,
                             void* ws, int blk, int gblk, ull* h,
                             unsigned haspos, unsigned sel1, unsigned sel2)
{
    const unsigned sel12 = (sel1 << 11) | sel2;
    constexpr int T = BR ? RT1 : RT0;
    constexpr int HW4 = BR ? HW1_4 : HW0_4;
    constexpr int HW  = BR ? HW1 : HW0;
    const int base = blk * BLK + (int)threadIdx.x;
    const float* glab_s = (const float*)glabel;

    unsigned pk[16];
    float g1v[16];
    if (STORED) {
        const uint4* pb4 = (const uint4*)pb_of(ws, BR);
#pragma unroll
        for (int i = 0; i < 4; i++) {
            uint4 q = pb4[base + i * T];
            pk[i*4+0]=q.x; pk[i*4+1]=q.y; pk[i*4+2]=q.z; pk[i*4+3]=q.w;
        }
    } else {
#pragma unroll
        for (int i = 0; i < 4; i++) {
            int id = base + i * T;
            int b = id / HW4, r = id - b * HW4;
            float4 s0 = score[(size_t)(b*2)*HW4 + r];
            float4 s1 = score[(size_t)(b*2+1)*HW4 + r];
            float4 g1 = glabel[(size_t)(b*6+1)*HW4 + r];
#pragma unroll
            for (int j = 0; j < 4; j++) {
                float a=(&s0.x)[j], cc=(&s1.x)[j];
                float m=fmaxf(a,cc);
                float e0=__expf(a-m), e1=__expf(cc-m);
                float p1=e1/(e0+e1);
                pk[i*4+j] = __float_as_uint(p1) | (((&g1.x)[j] > 0.5f) ? 0x80000000u : 0u);
                g1v[i*4+j] = (&g1.x)[j];
            }
        }
    }

    ull cnt_lt = 0;
    double ce_lt = 0.0;
    ull zpack = 0;
#pragma unroll
    for (int i = 0; i < 4; i++) {
#pragma unroll
        for (int j = 0; j < 4; j++) {
            unsigned raw = pk[i*4+j], pbv = raw & 0x7FFFFFFFu;
            unsigned npb = haspos ? ((raw >> 31) ? pbv : 0u) : pbv;
            bool iszero = (npb == 0);
            if (iszero && sel12 != 0) continue;  // accounted via base in scan_final
            unsigned b1 = npb >> 21, b2 = (npb >> 10) & 0x7FFu;
            bool lt = (b1 < sel1) || (b1 == sel1 && b2 < sel2);
            bool eq = ((npb >> 10) == sel12);
            if (lt || eq) {
                float g1s;
                if (STORED) {
                    int px = (base + i * T) * 4 + j;
                    int bb = px / HW, rr = px - bb * HW;
                    g1s = glab_s[(size_t)(bb * 6 + 1) * HW + rr];
                } else {
                    g1s = g1v[i*4+j];
                }
                float ce = -g1s * __logf(__uint_as_float(pbv));
                if (lt) { cnt_lt++; ce_lt += (double)ce; }
                else {
                    ull v = (1ull << 40) | (ull)__float2uint_rn(ce * CE_SCALE);
                    if (iszero) zpack += v;
                    else atomicAdd(&h[npb & 0x3FFu], v);
                }
            }
        }
    }
    if (zpack) atomicAdd(&h[0], zpack);

    ull CL = wred_q(cnt_lt);
    double CE = wred_d(ce_lt);
    __shared__ ull sq[4];
    __shared__ double sd[4];
    int t = threadIdx.x, w = t >> 6, lane = t & 63;
    if (lane == 0) { sq[w] = CL; sd[w] = CE; }
    __syncthreads();   // also orders LDS hist atomics before flush
    if (t == 0) {
        ull totc = sq[0] + sq[1] + sq[2] + sq[3];
        double totd = sd[0] + sd[1] + sd[2] + sd[3];
        ull* F = fin_of(ws, BR) + (size_t)(gblk & (REP2 - 1)) * 2;
        if (totc) atomicAdd(&F[0], totc);
        if (totd != 0.0) atomicAdd((double*)&F[1], totd);
    }
    const int rep = gblk & (REP2 - 1);
    ull* H = h3_of(ws, BR);
    for (int i = t; i < 1024; i += BLK) {
        ull v = h[i];
        if (v) atomicAdd(&H[(size_t)i * REP2 + rep], v);
    }
}

// ---- refine2': spare compaction duties + per-block select1 + tile work ----
template <bool STORED>
__global__ __launch_bounds__(256) void refine2_k2(
    const float4* __restrict__ sc0, const float4* __restrict__ lb0,
    const float4* __restrict__ sc1, const float4* __restrict__ lb1, void* ws)
{
    __shared__ unsigned h[2048];
    __shared__ unsigned pref[256];
    __shared__ unsigned shv[4];
    __shared__ ull shq[4];
    const int t = threadIdx.x;
    const int bid = blockIdx.x;

    // spare duties: compact h1 -> cnt1; reduce PN/CEP -> Acc; reduce DM -> Acc.
    if (bid < 8) {
        const int job = bid * BLK + t;            // 0..2047
        const int jbr = job >> 10, bin = job & 1023;
        const uint4* p = (const uint4*)(h1_of(ws, jbr) + (size_t)bin * REP1);
        unsigned s = 0;
#pragma unroll
        for (int r = 0; r < REP1 / 4; r++) { uint4 q = p[r]; s += q.x + q.y + q.z + q.w; }
        cnt1_of(ws)[job] = s;
    } else if (bid < 16) {
        const int i = (bid - 8) * BLK + t;        // 0..2047, valid < SBT
        ull pv = 0; double a = 0.0, b = 0.0; bool hi = false;
        if (i < SBT) {
            unsigned v = pn_part(ws)[i];
            double2 ce = cep_part(ws)[i];
            pv = (ull)(v & 0xFFFFu) | ((ull)(v >> 16) << 32);
            a = ce.x; b = ce.y; hi = (i >= SB0);
        }
        ull p0 = hi ? 0 : pv, p1 = hi ? pv : 0;
        double a0 = hi ? 0.0 : a, a1 = hi ? a : 0.0;
        double b0 = hi ? 0.0 : b, b1 = hi ? b : 0.0;
        p0 = wred_q(p0); p1 = wred_q(p1);
        a0 = wred_d(a0); a1 = wred_d(a1); b0 = wred_d(b0); b1 = wred_d(b1);
        if ((t & 63) == 0) {
            Acc* A = acc_of(ws);
            if (p0) atomicAdd(&A[0].pn, p0);
            if (p1) atomicAdd(&A[1].pn, p1);
            if (a0 != 0.0) atomicAdd(&A[0].ce0, a0);
            if (a1 != 0.0) atomicAdd(&A[1].ce0, a1);
            if (b0 != 0.0) atomicAdd(&A[0].ce1, b0);
            if (b1 != 0.0) atomicAdd(&A[1].ce1, b1);
        }
    } else if (bid < 32) {
        const int i = (bid - 16) * BLK + t;       // 0..4095, valid < 3200
        double d = 0.0, m = 0.0; bool hi = false;
        if (i < BBLK0 + BBLK1) {
            double2 v = dm_part(ws)[i];
            d = v.x; m = v.y; hi = (i >= BBLK0);
        }
        double d0 = hi ? 0.0 : d, d1 = hi ? d : 0.0;
        double m0 = hi ? 0.0 : m, m1 = hi ? m : 0.0;
        d0 = wred_d(d0); d1 = wred_d(d1); m0 = wred_d(m0); m1 = wred_d(m1);
        if ((t & 63) == 0) {
            Acc* A = acc_of(ws);
            if (d0 != 0.0) atomicAdd(&A[0].d2, d0);
            if (d1 != 0.0) atomicAdd(&A[1].d2, d1);
            if (m0 != 0.0) atomicAdd(&A[0].ms, m0);
            if (m1 != 0.0) atomicAdd(&A[1].ms, m1);
        }
    }

    const int br  = (bid < RB0) ? 0 : 1;
    const int blk = (bid < RB0) ? bid : bid - RB0;

    Sel1R s1;
    compute_sel1_raw(ws, br, s1, pref, shv, shq);
    if (s1.done) return;

    for (int i = t; i < 2048; i += BLK) h[i] = 0;
    __syncthreads();
    if (br == 0) refine2_body<0, STORED>(sc0, lb0, ws, blk, h, s1.haspos, s1.sel1);
    else         refine2_body<1, STORED>(sc1, lb1, ws, blk, h, s1.haspos, s1.sel1);
    __syncthreads();
    const int rep = bid & (REP2 - 1);
    unsigned* H = h2_of(ws, br);
    for (int i = t; i < 2048; i += BLK) {
        unsigned v = h[i];
        if (v) atomicAdd(&H[(size_t)i * REP2 + rep], v);
    }
}

// ---- refine3': spare h2 compaction + per-block select1 (compact) + select2 (raw h2) + tile ----
template <bool STORED>
__global__ __launch_bounds__(256) void refine3_k2(
    const float4* __restrict__ sc0, const float4* __restrict__ lb0,
    const float4* __restrict__ sc1, const float4* __restrict__ lb1, void* ws)
{
    __shared__ ull h[1024];
    __shared__ unsigned pref[256];
    __shared__ unsigned shv[4];
    const int t = threadIdx.x;
    const int bid = blockIdx.x;

    // spare duty: compact h2 -> cnt2 (for scan_final)
    if (bid < 16) {
        const int job = bid * BLK + t;            // 0..4095
        const int jbr = job >> 11, bin = job & 2047;
        const uint4* p = (const uint4*)(h2_of(ws, jbr) + (size_t)bin * REP2);
        uint4 q0 = p[0], q1 = p[1];
        cnt2_of(ws)[job] = q0.x + q0.y + q0.z + q0.w + q1.x + q1.y + q1.z + q1.w;
    }

    const int br  = (bid < RB0) ? 0 : 1;
    const int blk = (bid < RB0) ? bid : bid - RB0;

    Sel1R s1;
    compute_sel1_compact(ws, br, s1, pref, shv);
    if (s1.done) return;

    unsigned sel2, tnx2;
    compute_sel2(h2_of(ws, br), true, s1.tnext, sel2, tnx2, pref, shv);

    for (int i = t; i < 1024; i += BLK) h[i] = 0;
    __syncthreads();
    if (br == 0) refine3_body<0, STORED>(sc0, lb0, ws, blk, bid, h, s1.haspos, s1.sel1, sel2);
    else         refine3_body<1, STORED>(sc1, lb1, ws, blk, bid, h, s1.haspos, s1.sel1, sel2);
}

// ---- scan_final: single small block on compact data + h3/fin ----
__global__ __launch_bounds__(256) void scan_final(void* ws, float* out)
{
    const int t = threadIdx.x;
    __shared__ unsigned pref[256];
    __shared__ unsigned shv[4];
    __shared__ ull qscr[4];
    __shared__ double sls[2], slb[2];

    for (int br = 0; br < 2; br++) {
        const unsigned N = br ? N1 : N0;
        Acc* A = acc_of(ws) + br;
        ull pn = A->pn;
        unsigned P = (unsigned)(pn & 0xFFFFFFFFull);
        unsigned negn = (unsigned)(pn >> 32);
        double CE0 = A->ce0, CE1NN = A->ce1;
        double D = A->d2, M = A->ms;
        double lb = (M > 0.0) ? D / fmax(M, 1e-8) : 0.0;

        Sel1R s1;
        compute_sel1_compact(ws, br, s1, pref, shv);

        if (s1.done) {
            if (t == 0) {
                double cntd = (double)P + (double)(N - negn);
                if (cntd < 1.0) cntd = 1.0;
                sls[br] = (CE0 + CE1NN) / cntd;
                slb[br] = lb;
            }
            __syncthreads();
            continue;
        }

        unsigned sel2, tnx2;
        compute_sel2(cnt2_of(ws) + (size_t)br * 2048, false, s1.tnext, sel2, tnx2, pref, shv);

        // level-3 select on h3 (reduce REP2 inline)
        const ull* H3 = h3_of(ws, br);
        ull cev[4]; unsigned cnt[4], ssum = 0;
#pragma unroll
        for (int j = 0; j < 4; j++) {
            int i = t * 4 + j;
            ull e = 0;
#pragma unroll
            for (int r = 0; r < REP2; r++) e += H3[(size_t)i * REP2 + r];
            cev[j] = e;
            cnt[j] = (unsigned)(e >> 40);
            ssum += cnt[j];
        }
        unsigned target = tnx2;
        if (t == 0) { shv[0] = 0; shv[1] = 1; }
        __syncthreads();
        pref[t] = ssum;
        __syncthreads();
        for (int off = 1; off < 256; off <<= 1) {
            unsigned x = (t >= off) ? pref[t - off] : 0u;
            __syncthreads();
            pref[t] += x;
            __syncthreads();
        }
        unsigned tot = pref[255];
        if (target > tot) target = tot;
        unsigned before = pref[t] - ssum;
#pragma unroll
        for (int j = 0; j < 4; j++) {
            if (tot && before < target && before + cnt[j] >= target) {
                shv[0] = (unsigned)(t * 4 + j);
                shv[1] = target - before;
            }
            before += cnt[j];
        }
        __syncthreads();
        unsigned sel3 = shv[0];

        ull cei = 0;
#pragma unroll
        for (int j = 0; j < 4; j++) {
            unsigned bin = (unsigned)(t * 4 + j);
            if (bin <= sel3) cei += cev[j];
        }
        cei = wred_q(cei);
        int w = t >> 6;
        if ((t & 63) == 0) qscr[w] = cei;
        __syncthreads();
        if (t == 0) {
            ull CEI = qscr[0] + qscr[1] + qscr[2] + qscr[3];
            const ull* F = fin_of(ws, br);
            ull cl = 0; double cel = 0.0;
            for (int r = 0; r < REP2; r++) {
                cl += F[r * 2];
                cel += ((const double*)F)[r * 2 + 1];
            }
            unsigned sel12 = (s1.sel1 << 11) | sel2;
            double basec = (s1.haspos && sel12 != 0) ? (double)(N - negn) : 0.0;
            double basee = (s1.haspos && sel12 != 0) ? CE1NN : 0.0;
            double cntd = (double)P + basec + (double)cl + (double)(CEI >> 40);
            if (cntd < 1.0) cntd = 1.0;
            double ce = CE0 + basee + cel + (double)(CEI & MASK40) / (double)CE_SCALE;
            sls[br] = ce / cntd;
            slb[br] = lb;
        }
        __syncthreads();
    }

    if (t == 0) {
        out[0] = (float)(sls[0] + slb[0] + sls[1] + slb[1]);
        out[1] = (float)sls[0];
        out[2] = (float)slb[0];
        out[3] = (float)sls[1];
        out[4] = (float)slb[1];
    }
}

// ---------------- host ----------------
template <bool S>
static void run_pipeline(const float4* sc0, const float4* bb0, const float4* mk0, const float4* lb0,
                         const float4* sc1, const float4* bb1, const float4* mk1, const float4* lb1,
                         void* ws, float* out, hipStream_t stream)
{
    pass1<S><<<P1_GRID, BLK, 0, stream>>>(sc0, bb0, mk0, lb0, sc1, bb1, mk1, lb1, ws);
    refine2_k2<S><<<GRID_R, BLK, 0, stream>>>(sc0, lb0, sc1, lb1, ws);
    refine3_k2<S><<<GRID_R, BLK, 0, stream>>>(sc0, lb0, sc1, lb1, ws);
    scan_final<<<1, BLK, 0, stream>>>(ws, out);
}

extern "C" void kernel_launch(void* const* d_in, const int* in_sizes, int n_in,
                              void* d_out, int out_size, void* d_ws, size_t ws_size,
                              hipStream_t stream)
{
    (void)in_sizes; (void)n_in; (void)out_size;
    const float4* sc0 = (const float4*)d_in[0];
    const float4* bb0 = (const float4*)d_in[1];
    const float4* mk0 = (const float4*)d_in[2];
    const float4* lb0 = (const float4*)d_in[3];
    const float4* sc1 = (const float4*)d_in[4];
    const float4* bb1 = (const float4*)d_in[5];
    const float4* mk1 = (const float4*)d_in[6];
    const float4* lb1 = (const float4*)d_in[7];
    float* out = (float*)d_out;

    zero_ws_k<<<(ZERO_V4 + BLK - 1) / BLK, BLK, 0, stream>>>((uint4*)d_ws, ZERO_V4);

    if (ws_size >= WS_NEED)
        run_pipeline<true>(sc0, bb0, mk0, lb0, sc1, bb1, mk1, lb1, d_ws, out, stream);
    else
        run_pipeline<false>(sc0, bb0, mk0, lb0, sc1, bb1, mk1, lb1, d_ws, out, stream);
}